// Round 3
// baseline (1602.395 us; speedup 1.0000x reference)
//
#include <hip/hip_runtime.h>
#include <hip/hip_bf16.h>
#include <stdint.h>

// ---------------------------------------------------------------------------
// MMTransformer: B=32, IMG_LEN=49, TXT_LEN=77, L=126, D=512, H=8, HK=64,
// FF=2048, NB=4, IMG_DIM=768, VOCAB=49408.
// Round 2: runtime input-dtype detection (bf16 vs f32); all input-tensor
// reads and the final store are flag-aware; parameter offsets passed in
// ELEMENTS (dtype-independent); reg-staged LDS (no global_load_lds);
// ws_size guard with 123456.0 sentinel. Internal: bf16 MFMA, f32 accum,
// f32 residual stream.
// ---------------------------------------------------------------------------

using u16 = unsigned short;
typedef __attribute__((ext_vector_type(8))) __bf16 bf16x8v;
typedef __attribute__((ext_vector_type(4))) float f32x4;

__device__ __forceinline__ float bf2f(u16 u) {
  union { unsigned int i; float f; } x; x.i = ((unsigned int)u) << 16; return x.f;
}
__device__ __forceinline__ u16 f2bf(float f) {
  union { float f; unsigned int i; } u; u.f = f;
  unsigned int r = u.i + 0x7FFFu + ((u.i >> 16) & 1u);   // RNE
  return (u16)(r >> 16);
}
__device__ __forceinline__ float ld_f(const void* p, size_t i, int fl) {
  return fl ? ((const float*)p)[i] : bf2f(((const u16*)p)[i]);
}
__device__ __forceinline__ u16 ld_bf(const void* p, size_t i, int fl) {
  return fl ? f2bf(((const float*)p)[i]) : ((const u16*)p)[i];
}

// dtype detector: img_hidden ~ N(0,1). bf16 buffer -> ~0 implausible u16s;
// f32 buffer -> even-index u16s are mantissa bits, ~50-60% implausible.
__global__ void detect_kernel(const void* __restrict__ img, int* __restrict__ flag) {
  const int lane = threadIdx.x;
  const u16* p = (const u16*)img;
  int bad = 0;
#pragma unroll
  for (int i = 0; i < 4; ++i) {
    float v = bf2f(p[lane * 4 + i]);
    float av = fabsf(v);
    if (!(av <= 1e4f) || (av != 0.0f && av < 1e-30f)) bad++;  // NaN -> first term
  }
#pragma unroll
  for (int off = 32; off; off >>= 1) bad += __shfl_xor(bad, off, 64);
  if (lane == 0) flag[0] = (bad > 16) ? 1 : 0;
}

__global__ void sentinel_kernel(float* out) {
  out[blockIdx.x * 256 + threadIdx.x] = 123456.0f;
}

__global__ __launch_bounds__(256) void convert_kernel(
    const void* __restrict__ in, u16* __restrict__ out, int n,
    const int* __restrict__ fl) {
  const int fla = *fl;
  int i = blockIdx.x * 256 + threadIdx.x;
  if (i < n) out[i] = ld_bf(in, i, fla);
}

// ---------------------------------------------------------------------------
// bf16 MFMA GEMM: C[M,N] = A[M,K] @ Bt[N,K]^T (+ epilogue).
// boff = element offset into bias (and pos unused except EPI3).
// EPI 0: bf16 store (no bias). EPI 1: gelu(acc+bias) bf16. EPI 2: +bias+resid
// -> f32. EPI 3: img embed -> f32 x. EPI 4: +bias -> d_out (flag dtype).
// ---------------------------------------------------------------------------
template <int BM, int BN, int EPI>
__global__ __launch_bounds__(256) void gemm_kernel(
    const u16* __restrict__ A, const u16* __restrict__ Bt, void* Cout,
    const void* __restrict__ bias, long boff, const float* resid,
    const void* __restrict__ pos, int M, int N, int K,
    const int* __restrict__ fl)
{
  static_assert(BM == 64 || BM == 128, "");
  static_assert(BN == 64 || BN == 128, "");
  __shared__ __align__(16) u16 lA[BM * 32];
  __shared__ __align__(16) u16 lB[BN * 32];
  const int tid = threadIdx.x;
  const int lane = tid & 63, wid = tid >> 6;
  const int wm = wid >> 1, wn = wid & 1;
  constexpr int FM = BM / 32, FN = BN / 32;
  constexpr int ITA = BM / 64, ITB = BN / 64;
  const int tileM = blockIdx.x * BM, tileN = blockIdx.y * BN;

  f32x4 acc[FM][FN] = {};

  const int kSteps = K >> 5;
  for (int kt = 0; kt < kSteps; ++kt) {
    uint4 va[ITA], vb[ITB];
#pragma unroll
    for (int it = 0; it < ITA; ++it) {
      int ch = (wid * ITA + it) * 64 + lane;
      int row = ch >> 2, kc = ch & 3;
      int grow = tileM + row; grow = grow < M ? grow : (M - 1);
      va[it] = *(const uint4*)(A + (size_t)grow * K + kt * 32 + kc * 8);
    }
#pragma unroll
    for (int it = 0; it < ITB; ++it) {
      int ch = (wid * ITB + it) * 64 + lane;
      int row = ch >> 2, kc = ch & 3;
      vb[it] = *(const uint4*)(Bt + (size_t)(tileN + row) * K + kt * 32 + kc * 8);
    }
    __syncthreads();
#pragma unroll
    for (int it = 0; it < ITA; ++it) {
      int ch = (wid * ITA + it) * 64 + lane;
      *(uint4*)((char*)lA + ch * 16) = va[it];
    }
#pragma unroll
    for (int it = 0; it < ITB; ++it) {
      int ch = (wid * ITB + it) * 64 + lane;
      *(uint4*)((char*)lB + ch * 16) = vb[it];
    }
    __syncthreads();

    bf16x8v af[FM], bfr[FN];
#pragma unroll
    for (int fm = 0; fm < FM; ++fm) {
      int r = wm * (BM / 2) + fm * 16 + (lane & 15);
      af[fm] = *(const bf16x8v*)(lA + (r * 4 + (lane >> 4)) * 8);
    }
#pragma unroll
    for (int fn = 0; fn < FN; ++fn) {
      int r = wn * (BN / 2) + fn * 16 + (lane & 15);
      bfr[fn] = *(const bf16x8v*)(lB + (r * 4 + (lane >> 4)) * 8);
    }
#pragma unroll
    for (int fm = 0; fm < FM; ++fm)
#pragma unroll
      for (int fn = 0; fn < FN; ++fn)
        acc[fm][fn] = __builtin_amdgcn_mfma_f32_16x16x32_bf16(
            af[fm], bfr[fn], acc[fm][fn], 0, 0, 0);
  }

  const int fla = (EPI == 0) ? 0 : *fl;
  const int row0 = tileM + wm * (BM / 2);
  const int col0 = tileN + wn * (BN / 2);
#pragma unroll
  for (int fm = 0; fm < FM; ++fm) {
#pragma unroll
    for (int fn = 0; fn < FN; ++fn) {
      const int col = col0 + fn * 16 + (lane & 15);
      const int rb = row0 + fm * 16 + ((lane >> 4) << 2);
#pragma unroll
      for (int j = 0; j < 4; ++j) {
        const int row = rb + j;
        if (row < M) {
          float v = acc[fm][fn][j];
          if constexpr (EPI == 0) {
            ((u16*)Cout)[(size_t)row * N + col] = f2bf(v);
          } else if constexpr (EPI == 1) {
            float t = v + ld_f(bias, boff + col, fla);
            t = 0.5f * t * (1.0f + erff(t * 0.70710678118654752f));
            ((u16*)Cout)[(size_t)row * N + col] = f2bf(t);
          } else if constexpr (EPI == 2) {
            ((float*)Cout)[(size_t)row * N + col] =
                v + ld_f(bias, boff + col, fla) + resid[(size_t)row * N + col];
          } else if constexpr (EPI == 3) {
            int bb = row / 49, ll = row % 49;
            ((float*)Cout)[((size_t)(bb * 126 + ll)) * 512 + col] =
                v + ld_f(bias, boff + col, fla) + ld_f(pos, ll * 512 + col, fla);
          } else {
            float t = v + ld_f(bias, boff + col, fla);
            if (fla) ((float*)Cout)[(size_t)row * N + col] = t;
            else     ((u16*)Cout)[(size_t)row * N + col] = f2bf(t);
          }
        }
      }
    }
  }
}

// 32x32 tiled transpose: in [R][C] (flag dtype, z-batched) -> out [C][R] bf16.
__global__ __launch_bounds__(256) void transpose_any(
    const void* __restrict__ in, u16* __restrict__ out, int R, int C,
    const int* __restrict__ fl)
{
  const int fla = *fl;
  __shared__ u16 t[32][33];
  const size_t zo = (size_t)blockIdx.z * R * C;
  const int c0 = blockIdx.x * 32, r0 = blockIdx.y * 32;
  const int tx = threadIdx.x & 31, ty = threadIdx.x >> 5;
#pragma unroll
  for (int i = 0; i < 4; ++i)
    t[ty + 8 * i][tx] = ld_bf(in, zo + (size_t)(r0 + ty + 8 * i) * C + (c0 + tx), fla);
  __syncthreads();
#pragma unroll
  for (int i = 0; i < 4; ++i)
    out[zo + (size_t)(c0 + ty + 8 * i) * R + (r0 + tx)] = t[tx][ty + 8 * i];
}

// Attention: one block per (b, h, row-half). q,k,v internal bf16 [B*L][512].
__global__ __launch_bounds__(256) void attn_kernel(
    const u16* __restrict__ q, const u16* __restrict__ k,
    const u16* __restrict__ v, const int* __restrict__ amask,
    u16* __restrict__ o)
{
  const int b = blockIdx.x, hh = blockIdx.y, half = blockIdx.z;
  __shared__ float Kf[126 * 65];
  __shared__ u16 Vh[126 * 65];
  __shared__ float P[4][128];
  __shared__ float padK[128];
  const int tid = threadIdx.x, lane = tid & 63, wid = tid >> 6;

  for (int idx = tid; idx < 126 * 64; idx += 256) {
    int m = idx >> 6, kk = idx & 63;
    size_t src = ((size_t)(b * 126 + m)) * 512 + hh * 64 + kk;
    Kf[m * 65 + kk] = bf2f(k[src]);
    Vh[m * 65 + kk] = v[src];
  }
  for (int j = tid; j < 128; j += 256) {
    float kv = 0.0f;
    if (j < 49) kv = 1.0f;
    else if (j < 126) kv = (amask[b * 77 + (j - 49)] != 0) ? 1.0f : 0.0f;
    padK[j] = kv;
  }
  __syncthreads();

  const float scale = 0.04419417382415922f;  // 512^-0.5 (full-D, faithful)
  const int lbase = half * 63;
  for (int l = lbase + wid; l < lbase + 63; l += 4) {
    float qv = bf2f(q[((size_t)(b * 126 + l)) * 512 + hh * 64 + lane]);
    const int m0 = lane;
    const int m1v = lane + 64;
    const int m1 = m1v < 126 ? m1v : 125;
    const float* K0 = Kf + m0 * 65;
    const float* K1 = Kf + m1 * 65;
    float s0 = 0.f, s1 = 0.f;
#pragma unroll 8
    for (int kk = 0; kk < 64; ++kk) {
      float qs = __shfl(qv, kk, 64);
      s0 += qs * K0[kk];
      s1 += qs * K1[kk];
    }
    s0 *= scale; s1 *= scale;
    bool kp0 = (padK[m0] != 0.f) && (m0 < 49 || l < 49 || m0 <= l);
    bool kp1 = (padK[m1v] != 0.f) && (l < 49 || m1v <= l);
    float e0 = kp0 ? s0 : -1e30f;
    float e1 = kp1 ? s1 : -1e30f;
    float mx = fmaxf(e0, e1);
#pragma unroll
    for (int off = 32; off; off >>= 1) mx = fmaxf(mx, __shfl_xor(mx, off, 64));
    float p0 = kp0 ? __expf(s0 - mx) : 0.f;
    float p1 = kp1 ? __expf(s1 - mx) : 0.f;
    float sm = p0 + p1;
#pragma unroll
    for (int off = 32; off; off >>= 1) sm += __shfl_xor(sm, off, 64);
    float inv = 1.0f / sm;
    P[wid][lane] = p0 * inv;
    P[wid][lane + 64] = p1 * inv;
    float accv = 0.f;
#pragma unroll 6
    for (int m = 0; m < 126; ++m) accv += P[wid][m] * bf2f(Vh[m * 65 + lane]);
    o[((size_t)(b * 126 + l)) * 512 + hh * 64 + lane] = f2bf(accv);
  }
}

// LayerNorm over D=512 (x f32 -> bf16). goff = element offset into gam/bet.
template <int REMAP>
__global__ __launch_bounds__(256) void ln_kernel(
    const float* __restrict__ x, const void* __restrict__ gam,
    const void* __restrict__ bet, long goff, u16* __restrict__ out,
    const int* __restrict__ fl)
{
  const int fla = *fl;
  const int r = blockIdx.x;
  int srow, drow;
  if constexpr (REMAP) { int bb = r / 77, t = r % 77; srow = bb * 126 + 49 + t; drow = r; }
  else { srow = r; drow = r; }
  const float* xr = x + (size_t)srow * 512;
  const int tid = threadIdx.x, lane = tid & 63, wid = tid >> 6;
  float a = xr[tid], c = xr[tid + 256];
  float s = a + c;
#pragma unroll
  for (int off = 32; off; off >>= 1) s += __shfl_xor(s, off, 64);
  __shared__ float red0[4], red1[4];
  if (lane == 0) red0[wid] = s;
  __syncthreads();
  float mu = (red0[0] + red0[1] + red0[2] + red0[3]) * (1.0f / 512.0f);
  float da = a - mu, dc = c - mu;
  float q2 = da * da + dc * dc;
#pragma unroll
  for (int off = 32; off; off >>= 1) q2 += __shfl_xor(q2, off, 64);
  if (lane == 0) red1[wid] = q2;
  __syncthreads();
  float var = (red1[0] + red1[1] + red1[2] + red1[3]) * (1.0f / 512.0f);
  float inv = rsqrtf(var + 1e-5f);
  u16* orow = out + (size_t)drow * 512;
  orow[tid] = f2bf(da * inv * ld_f(gam, goff + tid, fla) + ld_f(bet, goff + tid, fla));
  orow[tid + 256] =
      f2bf(dc * inv * ld_f(gam, goff + tid + 256, fla) + ld_f(bet, goff + tid + 256, fla));
}

__global__ __launch_bounds__(256) void txt_embed_kernel(
    const void* __restrict__ txt, const void* __restrict__ pos,
    float* __restrict__ x, const int* __restrict__ fl)
{
  const int fla = *fl;
  int idx = blockIdx.x * 256 + threadIdx.x;
  if (idx < 32 * 77 * 512) {
    int d = idx & 511;
    int bt = idx >> 9;
    int t = bt % 77, bb = bt / 77;
    x[((size_t)(bb * 126 + 49 + t)) * 512 + d] =
        ld_f(txt, idx, fla) + ld_f(pos, (49 + t) * 512 + d, fla);
  }
}

// ---------------------------------------------------------------------------
extern "C" void kernel_launch(void* const* d_in, const int* in_sizes, int n_in,
                              void* d_out, int out_size, void* d_ws, size_t ws_size,
                              hipStream_t stream)
{
  (void)in_sizes; (void)n_in; (void)out_size;
  const void* img_hidden = d_in[0];
  const void* txt_emb    = d_in[1];
  const void* img_proj_w = d_in[2];
  const void* img_proj_b = d_in[3];
  const void* pos_embed  = d_in[4];
  const void* wq    = d_in[5];
  const void* wk    = d_in[6];
  const void* wv    = d_in[7];
  const void* w_proj = d_in[8];
  const void* b_proj = d_in[9];
  const void* ln1_g = d_in[10];
  const void* ln1_b = d_in[11];
  const void* ln2_g = d_in[12];
  const void* ln2_b = d_in[13];
  const void* fc1_w = d_in[14];
  const void* fc1_b = d_in[15];
  const void* fc2_w = d_in[16];
  const void* fc2_b = d_in[17];
  const void* lnf_g = d_in[18];
  const void* lnf_b = d_in[19];
  const void* out_w = d_in[20];
  const void* out_b = d_in[21];
  const int* amask  = (const int*)d_in[22];

  char* ws = (char*)d_ws;
  size_t off = 0;
  auto alloc = [&](size_t bytes) {
    void* p = ws + off; off += (bytes + 255) & ~(size_t)255; return p;
  };
  int* dflag = (int*)alloc(256);
  u16* imgbf = (u16*)alloc(1204224ull * 2);
  float* x   = (float*)alloc(4032ull * 512 * 4);
  u16* xl    = (u16*)alloc(2464ull * 512 * 2);
  const size_t uni0 = off;
  u16* imgwT = (u16*)alloc(512ull * 768 * 2);
  u16* qT    = (u16*)alloc(4ull * 512 * 512 * 2);
  u16* kT    = (u16*)alloc(4ull * 512 * 512 * 2);
  u16* vT    = (u16*)alloc(4ull * 512 * 512 * 2);
  u16* wpT   = (u16*)alloc(4ull * 512 * 512 * 2);
  u16* fc1T  = (u16*)alloc(4ull * 2048 * 512 * 2);
  u16* fc2T  = (u16*)alloc(4ull * 512 * 2048 * 2);
  u16* h     = (u16*)alloc(4032ull * 512 * 2);
  u16* qb    = (u16*)alloc(4032ull * 512 * 2);
  u16* kb    = (u16*)alloc(4032ull * 512 * 2);
  u16* vb    = (u16*)alloc(4032ull * 512 * 2);
  u16* ob    = (u16*)alloc(4032ull * 512 * 2);
  u16* ff    = (u16*)alloc(4032ull * 2048 * 2);
  u16* outwT = (u16*)(ws + uni0);   // 50.6 MB, aliases dead loop buffers

  if (ws_size < off) {
    sentinel_kernel<<<dim3(16), 256, 0, stream>>>((float*)d_out);
    return;
  }

  detect_kernel<<<dim3(1), 64, 0, stream>>>(img_hidden, dflag);
  convert_kernel<<<dim3(4704), 256, 0, stream>>>(img_hidden, imgbf, 1204224, dflag);

  transpose_any<<<dim3(16, 24, 1), 256, 0, stream>>>(img_proj_w, imgwT, 768, 512, dflag);
  transpose_any<<<dim3(2, 16, 32), 256, 0, stream>>>(wq, qT, 512, 64, dflag);
  transpose_any<<<dim3(2, 16, 32), 256, 0, stream>>>(wk, kT, 512, 64, dflag);
  transpose_any<<<dim3(2, 16, 32), 256, 0, stream>>>(wv, vT, 512, 64, dflag);
  transpose_any<<<dim3(16, 16, 4), 256, 0, stream>>>(w_proj, wpT, 512, 512, dflag);
  transpose_any<<<dim3(64, 16, 4), 256, 0, stream>>>(fc1_w, fc1T, 512, 2048, dflag);
  transpose_any<<<dim3(16, 64, 4), 256, 0, stream>>>(fc2_w, fc2T, 2048, 512, dflag);

  gemm_kernel<64, 64, 3><<<dim3(25, 8), 256, 0, stream>>>(
      imgbf, imgwT, x, img_proj_b, 0, nullptr, pos_embed, 1568, 512, 768, dflag);
  txt_embed_kernel<<<dim3(4928), 256, 0, stream>>>(txt_emb, pos_embed, x, dflag);

  for (int i = 0; i < 4; ++i) {
    ln_kernel<0><<<dim3(4032), 256, 0, stream>>>(x, ln1_g, ln1_b, i * 512, h, dflag);
    gemm_kernel<64, 64, 0><<<dim3(63, 8), 256, 0, stream>>>(
        h, qT + i * 262144, qb, nullptr, 0, nullptr, nullptr, 4032, 512, 512, dflag);
    gemm_kernel<64, 64, 0><<<dim3(63, 8), 256, 0, stream>>>(
        h, kT + i * 262144, kb, nullptr, 0, nullptr, nullptr, 4032, 512, 512, dflag);
    gemm_kernel<64, 64, 0><<<dim3(63, 8), 256, 0, stream>>>(
        h, vT + i * 262144, vb, nullptr, 0, nullptr, nullptr, 4032, 512, 512, dflag);
    attn_kernel<<<dim3(32, 8, 2), 256, 0, stream>>>(qb, kb, vb, amask, ob);
    gemm_kernel<64, 64, 2><<<dim3(63, 8), 256, 0, stream>>>(
        ob, wpT + i * 262144, x, b_proj, i * 512, x, nullptr, 4032, 512, 512, dflag);
    ln_kernel<0><<<dim3(4032), 256, 0, stream>>>(x, ln2_g, ln2_b, i * 512, h, dflag);
    gemm_kernel<64, 64, 1><<<dim3(63, 32), 256, 0, stream>>>(
        h, fc1T + i * 1048576, ff, fc1_b, i * 2048, nullptr, nullptr, 4032, 2048, 512, dflag);
    gemm_kernel<64, 64, 2><<<dim3(63, 8), 256, 0, stream>>>(
        ff, fc2T + i * 1048576, x, fc2_b, i * 512, x, nullptr, 4032, 512, 2048, dflag);
  }

  ln_kernel<1><<<dim3(2464), 256, 0, stream>>>(x, lnf_g, lnf_b, 0, xl, dflag);
  transpose_any<<<dim3(1544, 16, 1), 256, 0, stream>>>(out_w, outwT, 512, 49408, dflag);
  gemm_kernel<128, 128, 4><<<dim3(20, 386), 256, 0, stream>>>(
      xl, outwT, d_out, out_b, 0, nullptr, nullptr, 2464, 49408, 512, dflag);
}

// Round 4
// 1191.444 us; speedup vs baseline: 1.3449x; 1.3449x over previous
//
#include <hip/hip_runtime.h>
#include <hip/hip_bf16.h>
#include <stdint.h>

// ---------------------------------------------------------------------------
// MMTransformer: B=32, IMG_LEN=49, TXT_LEN=77, L=126, D=512, H=8, HK=64,
// FF=2048, NB=4, IMG_DIM=768, VOCAB=49408.
// Round 3: (1) LDS-staged coalesced epilogues (kill 2.8x write amplification
// on the 487 MB f32 vocab output); (2) global_load_lds width-16 staging
// (dtype bug is fixed; m151: +35% vs reg-staging); (3) 64x128 layer tiles +
// fused QKV GEMM (N=1536). Internal: bf16 MFMA 16x16x32, f32 accum, f32
// residual stream; runtime input-dtype detection retained.
// ---------------------------------------------------------------------------

using u16 = unsigned short;
typedef __attribute__((ext_vector_type(8))) __bf16 bf16x8v;
typedef __attribute__((ext_vector_type(4))) float f32x4;

__device__ __forceinline__ float bf2f(u16 u) {
  union { unsigned int i; float f; } x; x.i = ((unsigned int)u) << 16; return x.f;
}
__device__ __forceinline__ u16 f2bf(float f) {
  union { float f; unsigned int i; } u; u.f = f;
  unsigned int r = u.i + 0x7FFFu + ((u.i >> 16) & 1u);   // RNE
  return (u16)(r >> 16);
}
__device__ __forceinline__ float ld_f(const void* p, size_t i, int fl) {
  return fl ? ((const float*)p)[i] : bf2f(((const u16*)p)[i]);
}
__device__ __forceinline__ u16 ld_bf(const void* p, size_t i, int fl) {
  return fl ? f2bf(((const float*)p)[i]) : ((const u16*)p)[i];
}

// async global->LDS, 16B per lane; LDS dest = wave-uniform base + lane*16.
__device__ __forceinline__ void async_copy16(const void* g, void* l) {
  __builtin_amdgcn_global_load_lds(
      (__attribute__((address_space(1))) void*)(g),
      (__attribute__((address_space(3))) void*)(l), 16, 0, 0);
}

// dtype detector: img_hidden ~ N(0,1). bf16 buffer -> ~0 implausible u16s;
// f32 buffer -> even-index u16s are mantissa bits, ~50-60% implausible.
__global__ void detect_kernel(const void* __restrict__ img, int* __restrict__ flag) {
  const int lane = threadIdx.x;
  const u16* p = (const u16*)img;
  int bad = 0;
#pragma unroll
  for (int i = 0; i < 4; ++i) {
    float v = bf2f(p[lane * 4 + i]);
    float av = fabsf(v);
    if (!(av <= 1e4f) || (av != 0.0f && av < 1e-30f)) bad++;
  }
#pragma unroll
  for (int off = 32; off; off >>= 1) bad += __shfl_xor(bad, off, 64);
  if (lane == 0) flag[0] = (bad > 16) ? 1 : 0;
}

__global__ void sentinel_kernel(float* out) {
  out[blockIdx.x * 256 + threadIdx.x] = 123456.0f;
}

__global__ __launch_bounds__(256) void convert_kernel(
    const void* __restrict__ in, u16* __restrict__ out, int n,
    const int* __restrict__ fl) {
  const int fla = *fl;
  int i = blockIdx.x * 256 + threadIdx.x;
  if (i < n) out[i] = ld_bf(in, i, fla);
}

// ---------------------------------------------------------------------------
// bf16 MFMA GEMM: C[M,N] = A[M,K] @ Bt[N,K]^T (+ epilogue). BN = 128.
// EPI 0: bf16 store (no bias), LDS-coalesced.
// EPI 1: gelu(acc+bias) -> bf16, LDS-coalesced.
// EPI 2: acc+bias+resid -> f32 (residual update, direct store; small output)
// EPI 3: img embed -> f32 x (direct)
// EPI 4: acc+bias -> d_out, dtype per flag; LDS-coalesced both paths.
// ---------------------------------------------------------------------------
template <int BM, int BN, int EPI>
__global__ __launch_bounds__(256) void gemm_kernel(
    const u16* __restrict__ A, const u16* __restrict__ Bt, void* Cout,
    const void* __restrict__ bias, long boff, const float* resid,
    const void* __restrict__ pos, int M, int N, int K,
    const int* __restrict__ fl)
{
  static_assert(BN == 128, "");
  static_assert(BM == 64 || BM == 128, "");
  constexpr int STAGE_B = BM * 64 + BN * 64;           // A,B tiles (BK=32 bf16)
  constexpr int EPI_B = (EPI == 0 || EPI == 1 || EPI == 4) ? BM * BN * 2 : 0;
  constexpr int SMEM_B = STAGE_B > EPI_B ? STAGE_B : EPI_B;
  __shared__ __align__(16) char smem[SMEM_B];
  u16* lA = (u16*)smem;
  u16* lB = (u16*)(smem + BM * 64);

  const int tid = threadIdx.x;
  const int lane = tid & 63, wid = tid >> 6;
  const int wm = wid >> 1, wn = wid & 1;               // 2x2 wave grid
  constexpr int FM = BM / 32, FN = 4;                  // 16x16 frags per wave
  constexpr int ITA = BM / 64, ITB = BN / 64;          // gload_lds instrs/wave
  const int tileM = blockIdx.x * BM, tileN = blockIdx.y * BN;

  f32x4 acc[FM][FN] = {};

  const int kSteps = K >> 5;
  for (int kt = 0; kt < kSteps; ++kt) {
    __syncthreads();  // previous iteration's readers done
#pragma unroll
    for (int it = 0; it < ITA; ++it) {
      int ch = (wid * ITA + it) * 64 + lane;           // 16B-chunk index
      int row = ch >> 2, kc = ch & 3;
      int grow = tileM + row; grow = grow < M ? grow : (M - 1);
      async_copy16(A + (size_t)grow * K + kt * 32 + kc * 8,
                   smem + (wid * ITA + it) * 1024);
    }
#pragma unroll
    for (int it = 0; it < ITB; ++it) {
      int ch = (wid * ITB + it) * 64 + lane;
      int row = ch >> 2, kc = ch & 3;
      async_copy16(Bt + (size_t)(tileN + row) * K + kt * 32 + kc * 8,
                   smem + BM * 64 + (wid * ITB + it) * 1024);
    }
    __syncthreads();  // compiler drains vmcnt before barrier

    bf16x8v af[FM], bfr[FN];
#pragma unroll
    for (int fm = 0; fm < FM; ++fm) {
      int r = wm * (BM / 2) + fm * 16 + (lane & 15);
      af[fm] = *(const bf16x8v*)(lA + (r * 4 + (lane >> 4)) * 8);
    }
#pragma unroll
    for (int fn = 0; fn < FN; ++fn) {
      int r = wn * 64 + fn * 16 + (lane & 15);
      bfr[fn] = *(const bf16x8v*)(lB + (r * 4 + (lane >> 4)) * 8);
    }
#pragma unroll
    for (int fm = 0; fm < FM; ++fm)
#pragma unroll
      for (int fn = 0; fn < FN; ++fn)
        acc[fm][fn] = __builtin_amdgcn_mfma_f32_16x16x32_bf16(
            af[fm], bfr[fn], acc[fm][fn], 0, 0, 0);
  }

  const int fla = (EPI == 0) ? 0 : *fl;
  const int row0l = wm * (BM / 2);
  const int col0l = wn * 64;

  if constexpr (EPI == 0 || EPI == 1 || EPI == 4) {
    if (EPI == 4 && fla) {
      // f32 output: two half-tile passes through LDS, fully coalesced writes.
      float* epf = (float*)smem;
#pragma unroll
      for (int p = 0; p < 2; ++p) {
        __syncthreads();
        if (wm == p) {
#pragma unroll
          for (int fm = 0; fm < FM; ++fm)
#pragma unroll
            for (int fn = 0; fn < FN; ++fn)
#pragma unroll
              for (int j = 0; j < 4; ++j) {
                int rl = fm * 16 + ((lane >> 4) << 2) + j;   // row within half
                int cl = col0l + fn * 16 + (lane & 15);
                epf[rl * BN + cl] =
                    acc[fm][fn][j] + ld_f(bias, boff + tileN + cl, fla);
              }
        }
        __syncthreads();
        for (int r = tid >> 5; r < BM / 2; r += 8) {
          int grow = tileM + p * (BM / 2) + r;
          if (grow < M)
            *(uint4*)((float*)Cout + (size_t)grow * N + tileN + (tid & 31) * 4) =
                *(const uint4*)(epf + r * BN + (tid & 31) * 4);
        }
      }
    } else {
      // bf16 output: full-tile u16 staging, coalesced 16B-chunk writes.
      u16* ep = (u16*)smem;
      __syncthreads();
#pragma unroll
      for (int fm = 0; fm < FM; ++fm)
#pragma unroll
        for (int fn = 0; fn < FN; ++fn)
#pragma unroll
          for (int j = 0; j < 4; ++j) {
            int rl = row0l + fm * 16 + ((lane >> 4) << 2) + j;
            int cl = col0l + fn * 16 + (lane & 15);
            float t = acc[fm][fn][j];
            if constexpr (EPI == 1) {
              t += ld_f(bias, boff + tileN + cl, fla);
              t = 0.5f * t * (1.0f + erff(t * 0.70710678118654752f));
            } else if constexpr (EPI == 4) {
              t += ld_f(bias, boff + tileN + cl, fla);
            }
            ep[rl * BN + cl] = f2bf(t);
          }
      __syncthreads();
      for (int r = tid >> 4; r < BM; r += 16) {
        int grow = tileM + r;
        if (grow < M)
          *(uint4*)((u16*)Cout + (size_t)grow * N + tileN + (tid & 15) * 8) =
              *(const uint4*)(ep + r * BN + (tid & 15) * 8);
      }
    }
  } else {
    // EPI 2/3: direct f32 stores (small outputs).
#pragma unroll
    for (int fm = 0; fm < FM; ++fm) {
#pragma unroll
      for (int fn = 0; fn < FN; ++fn) {
        const int col = tileN + col0l + fn * 16 + (lane & 15);
        const int rb = tileM + row0l + fm * 16 + ((lane >> 4) << 2);
#pragma unroll
        for (int j = 0; j < 4; ++j) {
          const int row = rb + j;
          if (row < M) {
            float v = acc[fm][fn][j];
            if constexpr (EPI == 2) {
              ((float*)Cout)[(size_t)row * N + col] =
                  v + ld_f(bias, boff + col, fla) + resid[(size_t)row * N + col];
            } else {
              int bb = row / 49, ll = row % 49;
              ((float*)Cout)[((size_t)(bb * 126 + ll)) * 512 + col] =
                  v + ld_f(bias, boff + col, fla) + ld_f(pos, ll * 512 + col, fla);
            }
          }
        }
      }
    }
  }
}

// 32x32 tiled transpose: in [R][C] (flag dtype, z-batched) -> out [C][R] bf16.
__global__ __launch_bounds__(256) void transpose_any(
    const void* __restrict__ in, u16* __restrict__ out, int R, int C,
    const int* __restrict__ fl)
{
  const int fla = *fl;
  __shared__ u16 t[32][33];
  const size_t zo = (size_t)blockIdx.z * R * C;
  const int c0 = blockIdx.x * 32, r0 = blockIdx.y * 32;
  const int tx = threadIdx.x & 31, ty = threadIdx.x >> 5;
#pragma unroll
  for (int i = 0; i < 4; ++i)
    t[ty + 8 * i][tx] = ld_bf(in, zo + (size_t)(r0 + ty + 8 * i) * C + (c0 + tx), fla);
  __syncthreads();
#pragma unroll
  for (int i = 0; i < 4; ++i)
    out[zo + (size_t)(c0 + ty + 8 * i) * R + (r0 + tx)] = t[tx][ty + 8 * i];
}

// wq/wk/wv [4][8][512][64] -> qkvT [4][1536][512], head h rows at h*64+obase.
__global__ __launch_bounds__(256) void transpose_qkv(
    const void* __restrict__ in, u16* __restrict__ out, int obase,
    const int* __restrict__ fl)
{
  const int fla = *fl;
  __shared__ u16 t[32][33];
  const int z = blockIdx.z, li = z >> 3, hh = z & 7;
  const size_t zi = (size_t)z * 512 * 64;
  const size_t zo = (size_t)li * (1536 * 512) + (size_t)(obase + hh * 64) * 512;
  const int c0 = blockIdx.x * 32, r0 = blockIdx.y * 32;   // c over 64, r over 512
  const int tx = threadIdx.x & 31, ty = threadIdx.x >> 5;
#pragma unroll
  for (int i = 0; i < 4; ++i)
    t[ty + 8 * i][tx] = ld_bf(in, zi + (size_t)(r0 + ty + 8 * i) * 64 + (c0 + tx), fla);
  __syncthreads();
#pragma unroll
  for (int i = 0; i < 4; ++i)
    out[zo + (size_t)(c0 + ty + 8 * i) * 512 + (r0 + tx)] = t[tx][ty + 8 * i];
}

// Attention: one block per (b, h, row-half). qkv packed [B*L][1536].
__global__ __launch_bounds__(256) void attn_kernel(
    const u16* __restrict__ qkv, const int* __restrict__ amask,
    u16* __restrict__ o)
{
  const int b = blockIdx.x, hh = blockIdx.y, half = blockIdx.z;
  __shared__ float Kf[126 * 65];
  __shared__ u16 Vh[126 * 65];
  __shared__ float P[4][128];
  __shared__ float padK[128];
  const int tid = threadIdx.x, lane = tid & 63, wid = tid >> 6;

  for (int idx = tid; idx < 126 * 64; idx += 256) {
    int m = idx >> 6, kk = idx & 63;
    size_t base = ((size_t)(b * 126 + m)) * 1536 + hh * 64 + kk;
    Kf[m * 65 + kk] = bf2f(qkv[base + 512]);
    Vh[m * 65 + kk] = qkv[base + 1024];
  }
  for (int j = tid; j < 128; j += 256) {
    float kv = 0.0f;
    if (j < 49) kv = 1.0f;
    else if (j < 126) kv = (amask[b * 77 + (j - 49)] != 0) ? 1.0f : 0.0f;
    padK[j] = kv;
  }
  __syncthreads();

  const float scale = 0.04419417382415922f;  // 512^-0.5 (full-D, faithful)
  const int lbase = half * 63;
  for (int l = lbase + wid; l < lbase + 63; l += 4) {
    float qv = bf2f(qkv[((size_t)(b * 126 + l)) * 1536 + hh * 64 + lane]);
    const int m0 = lane;
    const int m1v = lane + 64;
    const int m1 = m1v < 126 ? m1v : 125;
    const float* K0 = Kf + m0 * 65;
    const float* K1 = Kf + m1 * 65;
    float s0 = 0.f, s1 = 0.f;
#pragma unroll 8
    for (int kk = 0; kk < 64; ++kk) {
      float qs = __shfl(qv, kk, 64);
      s0 += qs * K0[kk];
      s1 += qs * K1[kk];
    }
    s0 *= scale; s1 *= scale;
    bool kp0 = (padK[m0] != 0.f) && (m0 < 49 || l < 49 || m0 <= l);
    bool kp1 = (padK[m1v] != 0.f) && (l < 49 || m1v <= l);
    float e0 = kp0 ? s0 : -1e30f;
    float e1 = kp1 ? s1 : -1e30f;
    float mx = fmaxf(e0, e1);
#pragma unroll
    for (int off = 32; off; off >>= 1) mx = fmaxf(mx, __shfl_xor(mx, off, 64));
    float p0 = kp0 ? __expf(s0 - mx) : 0.f;
    float p1 = kp1 ? __expf(s1 - mx) : 0.f;
    float sm = p0 + p1;
#pragma unroll
    for (int off = 32; off; off >>= 1) sm += __shfl_xor(sm, off, 64);
    float inv = 1.0f / sm;
    P[wid][lane] = p0 * inv;
    P[wid][lane + 64] = p1 * inv;
    float accv = 0.f;
#pragma unroll 6
    for (int m = 0; m < 126; ++m) accv += P[wid][m] * bf2f(Vh[m * 65 + lane]);
    o[((size_t)(b * 126 + l)) * 512 + hh * 64 + lane] = f2bf(accv);
  }
}

// LayerNorm over D=512 (x f32 -> bf16). goff = element offset into gam/bet.
template <int REMAP>
__global__ __launch_bounds__(256) void ln_kernel(
    const float* __restrict__ x, const void* __restrict__ gam,
    const void* __restrict__ bet, long goff, u16* __restrict__ out,
    const int* __restrict__ fl)
{
  const int fla = *fl;
  const int r = blockIdx.x;
  int srow, drow;
  if constexpr (REMAP) { int bb = r / 77, t = r % 77; srow = bb * 126 + 49 + t; drow = r; }
  else { srow = r; drow = r; }
  const float* xr = x + (size_t)srow * 512;
  const int tid = threadIdx.x, lane = tid & 63, wid = tid >> 6;
  float a = xr[tid], c = xr[tid + 256];
  float s = a + c;
#pragma unroll
  for (int off = 32; off; off >>= 1) s += __shfl_xor(s, off, 64);
  __shared__ float red0[4], red1[4];
  if (lane == 0) red0[wid] = s;
  __syncthreads();
  float mu = (red0[0] + red0[1] + red0[2] + red0[3]) * (1.0f / 512.0f);
  float da = a - mu, dc = c - mu;
  float q2 = da * da + dc * dc;
#pragma unroll
  for (int off = 32; off; off >>= 1) q2 += __shfl_xor(q2, off, 64);
  if (lane == 0) red1[wid] = q2;
  __syncthreads();
  float var = (red1[0] + red1[1] + red1[2] + red1[3]) * (1.0f / 512.0f);
  float inv = rsqrtf(var + 1e-5f);
  u16* orow = out + (size_t)drow * 512;
  orow[tid] = f2bf(da * inv * ld_f(gam, goff + tid, fla) + ld_f(bet, goff + tid, fla));
  orow[tid + 256] =
      f2bf(dc * inv * ld_f(gam, goff + tid + 256, fla) + ld_f(bet, goff + tid + 256, fla));
}

__global__ __launch_bounds__(256) void txt_embed_kernel(
    const void* __restrict__ txt, const void* __restrict__ pos,
    float* __restrict__ x, const int* __restrict__ fl)
{
  const int fla = *fl;
  int idx = blockIdx.x * 256 + threadIdx.x;
  if (idx < 32 * 77 * 512) {
    int d = idx & 511;
    int bt = idx >> 9;
    int t = bt % 77, bb = bt / 77;
    x[((size_t)(bb * 126 + 49 + t)) * 512 + d] =
        ld_f(txt, idx, fla) + ld_f(pos, (49 + t) * 512 + d, fla);
  }
}

// ---------------------------------------------------------------------------
extern "C" void kernel_launch(void* const* d_in, const int* in_sizes, int n_in,
                              void* d_out, int out_size, void* d_ws, size_t ws_size,
                              hipStream_t stream)
{
  (void)in_sizes; (void)n_in; (void)out_size;
  const void* img_hidden = d_in[0];
  const void* txt_emb    = d_in[1];
  const void* img_proj_w = d_in[2];
  const void* img_proj_b = d_in[3];
  const void* pos_embed  = d_in[4];
  const void* wq    = d_in[5];
  const void* wk    = d_in[6];
  const void* wv    = d_in[7];
  const void* w_proj = d_in[8];
  const void* b_proj = d_in[9];
  const void* ln1_g = d_in[10];
  const void* ln1_b = d_in[11];
  const void* ln2_g = d_in[12];
  const void* ln2_b = d_in[13];
  const void* fc1_w = d_in[14];
  const void* fc1_b = d_in[15];
  const void* fc2_w = d_in[16];
  const void* fc2_b = d_in[17];
  const void* lnf_g = d_in[18];
  const void* lnf_b = d_in[19];
  const void* out_w = d_in[20];
  const void* out_b = d_in[21];
  const int* amask  = (const int*)d_in[22];

  char* ws = (char*)d_ws;
  size_t off = 0;
  auto alloc = [&](size_t bytes) {
    void* p = ws + off; off += (bytes + 255) & ~(size_t)255; return p;
  };
  int* dflag = (int*)alloc(256);
  u16* imgbf = (u16*)alloc(1204224ull * 2);
  float* x   = (float*)alloc(4032ull * 512 * 4);
  u16* xl    = (u16*)alloc(2464ull * 512 * 2);
  const size_t uni0 = off;
  u16* imgwT = (u16*)alloc(512ull * 768 * 2);
  u16* qkvT  = (u16*)alloc(4ull * 1536 * 512 * 2);
  u16* wpT   = (u16*)alloc(4ull * 512 * 512 * 2);
  u16* fc1T  = (u16*)alloc(4ull * 2048 * 512 * 2);
  u16* fc2T  = (u16*)alloc(4ull * 512 * 2048 * 2);
  u16* h     = (u16*)alloc(4032ull * 512 * 2);
  u16* qkvb  = (u16*)alloc(4032ull * 1536 * 2);
  u16* ob    = (u16*)alloc(4032ull * 512 * 2);
  u16* ff    = (u16*)alloc(4032ull * 2048 * 2);
  u16* outwT = (u16*)(ws + uni0);   // 50.6 MB, aliases dead loop buffers

  if (ws_size < off) {
    sentinel_kernel<<<dim3(16), 256, 0, stream>>>((float*)d_out);
    return;
  }

  detect_kernel<<<dim3(1), 64, 0, stream>>>(img_hidden, dflag);
  convert_kernel<<<dim3(4704), 256, 0, stream>>>(img_hidden, imgbf, 1204224, dflag);

  transpose_any<<<dim3(16, 24, 1), 256, 0, stream>>>(img_proj_w, imgwT, 768, 512, dflag);
  transpose_qkv<<<dim3(2, 16, 32), 256, 0, stream>>>(wq, qkvT, 0, dflag);
  transpose_qkv<<<dim3(2, 16, 32), 256, 0, stream>>>(wk, qkvT, 512, dflag);
  transpose_qkv<<<dim3(2, 16, 32), 256, 0, stream>>>(wv, qkvT, 1024, dflag);
  transpose_any<<<dim3(16, 16, 4), 256, 0, stream>>>(w_proj, wpT, 512, 512, dflag);
  transpose_any<<<dim3(64, 16, 4), 256, 0, stream>>>(fc1_w, fc1T, 512, 2048, dflag);
  transpose_any<<<dim3(16, 64, 4), 256, 0, stream>>>(fc2_w, fc2T, 2048, 512, dflag);

  gemm_kernel<64, 128, 3><<<dim3(25, 4), 256, 0, stream>>>(
      imgbf, imgwT, x, img_proj_b, 0, nullptr, pos_embed, 1568, 512, 768, dflag);
  txt_embed_kernel<<<dim3(4928), 256, 0, stream>>>(txt_emb, pos_embed, x, dflag);

  for (int i = 0; i < 4; ++i) {
    ln_kernel<0><<<dim3(4032), 256, 0, stream>>>(x, ln1_g, ln1_b, i * 512, h, dflag);
    gemm_kernel<64, 128, 0><<<dim3(63, 12), 256, 0, stream>>>(
        h, qkvT + i * 786432, qkvb, nullptr, 0, nullptr, nullptr, 4032, 1536, 512, dflag);
    attn_kernel<<<dim3(32, 8, 2), 256, 0, stream>>>(qkvb, amask, ob);
    gemm_kernel<64, 128, 2><<<dim3(63, 4), 256, 0, stream>>>(
        ob, wpT + i * 262144, x, b_proj, i * 512, x, nullptr, 4032, 512, 512, dflag);
    ln_kernel<0><<<dim3(4032), 256, 0, stream>>>(x, ln2_g, ln2_b, i * 512, h, dflag);
    gemm_kernel<64, 128, 1><<<dim3(63, 16), 256, 0, stream>>>(
        h, fc1T + i * 1048576, ff, fc1_b, i * 2048, nullptr, nullptr, 4032, 2048, 512, dflag);
    gemm_kernel<64, 128, 2><<<dim3(63, 4), 256, 0, stream>>>(
        ff, fc2T + i * 1048576, x, fc2_b, i * 512, x, nullptr, 4032, 512, 2048, dflag);
  }

  ln_kernel<1><<<dim3(2464), 256, 0, stream>>>(x, lnf_g, lnf_b, 0, xl, dflag);
  transpose_any<<<dim3(1544, 16, 1), 256, 0, stream>>>(out_w, outwT, 512, 49408, dflag);
  gemm_kernel<128, 128, 4><<<dim3(20, 386), 256, 0, stream>>>(
      xl, outwT, d_out, out_b, 0, nullptr, nullptr, 2464, 49408, 512, dflag);
}

// Round 5
// 1108.437 us; speedup vs baseline: 1.4456x; 1.0749x over previous
//
#include <hip/hip_runtime.h>
#include <hip/hip_bf16.h>
#include <stdint.h>

// ---------------------------------------------------------------------------
// MMTransformer: B=32, IMG_LEN=49, TXT_LEN=77, L=126, D=512, H=8, HK=64,
// FF=2048, NB=4, IMG_DIM=768, VOCAB=49408.
// Round 4: (1) BK=64 K-steps (half the barriers per MFMA); (2) conflict-free
// LDS via chunk-XOR swizzle applied on BOTH stage-source and ds_read side
// (linear global_load_lds dest, rule #21); (3) bijective XCD-aware block
// swizzle, M-fastest per XCD (B-panel L2 reuse); (4) all f32 epilogues
// LDS-staged/coalesced. Internal: bf16 MFMA 16x16x32, f32 accum, f32
// residual stream; runtime input-dtype detection retained.
// ---------------------------------------------------------------------------

using u16 = unsigned short;
typedef __attribute__((ext_vector_type(8))) __bf16 bf16x8v;
typedef __attribute__((ext_vector_type(4))) float f32x4;

__device__ __forceinline__ float bf2f(u16 u) {
  union { unsigned int i; float f; } x; x.i = ((unsigned int)u) << 16; return x.f;
}
__device__ __forceinline__ u16 f2bf(float f) {
  union { float f; unsigned int i; } u; u.f = f;
  unsigned int r = u.i + 0x7FFFu + ((u.i >> 16) & 1u);   // RNE
  return (u16)(r >> 16);
}
__device__ __forceinline__ float ld_f(const void* p, size_t i, int fl) {
  return fl ? ((const float*)p)[i] : bf2f(((const u16*)p)[i]);
}
__device__ __forceinline__ u16 ld_bf(const void* p, size_t i, int fl) {
  return fl ? f2bf(((const float*)p)[i]) : ((const u16*)p)[i];
}

// async global->LDS, 16B per lane; LDS dest = wave-uniform base + lane*16.
__device__ __forceinline__ void async_copy16(const void* g, void* l) {
  __builtin_amdgcn_global_load_lds(
      (__attribute__((address_space(1))) void*)(g),
      (__attribute__((address_space(3))) void*)(l), 16, 0, 0);
}

// dtype detector: img_hidden ~ N(0,1). bf16 buffer -> ~0 implausible u16s;
// f32 buffer -> even-index u16s are mantissa bits, ~50-60% implausible.
__global__ void detect_kernel(const void* __restrict__ img, int* __restrict__ flag) {
  const int lane = threadIdx.x;
  const u16* p = (const u16*)img;
  int bad = 0;
#pragma unroll
  for (int i = 0; i < 4; ++i) {
    float v = bf2f(p[lane * 4 + i]);
    float av = fabsf(v);
    if (!(av <= 1e4f) || (av != 0.0f && av < 1e-30f)) bad++;
  }
#pragma unroll
  for (int off = 32; off; off >>= 1) bad += __shfl_xor(bad, off, 64);
  if (lane == 0) flag[0] = (bad > 16) ? 1 : 0;
}

__global__ void sentinel_kernel(float* out) {
  out[blockIdx.x * 256 + threadIdx.x] = 123456.0f;
}

__global__ __launch_bounds__(256) void convert_kernel(
    const void* __restrict__ in, u16* __restrict__ out, int n,
    const int* __restrict__ fl) {
  const int fla = *fl;
  int i = blockIdx.x * 256 + threadIdx.x;
  if (i < n) out[i] = ld_bf(in, i, fla);
}

// ---------------------------------------------------------------------------
// bf16 MFMA GEMM: C[M,N] = A[M,K] @ Bt[N,K]^T (+ epilogue). BN=128, BK=64.
// 1D grid with bijective XCD swizzle; gridM = # of M-tiles (M-fastest/XCD).
// LDS tiles [rows][64] bf16 with 16B-chunk XOR swizzle: slot s of row r
// holds global k-chunk s^(r&7)  ->  conflict-free ds_read_b128.
// EPI 0: bf16 (no bias). EPI 1: gelu(acc+bias) bf16. EPI 2: acc+bias+resid
// f32. EPI 3: img embed f32 (+pos, row remap). EPI 4: acc+bias -> d_out.
// ---------------------------------------------------------------------------
template <int BM, int BN, int EPI>
__global__ __launch_bounds__(256) void gemm_kernel(
    const u16* __restrict__ A, const u16* __restrict__ Bt, void* Cout,
    const void* __restrict__ bias, long boff, const float* resid,
    const void* __restrict__ pos, int M, int N, int K, int gridM,
    const int* __restrict__ fl)
{
  static_assert(BN == 128, "");
  static_assert(BM == 64 || BM == 128, "");
  constexpr int STAGE_B = BM * 128 + BN * 128;          // A,B tiles (BK=64)
  constexpr int EPI_B = BM * BN * 2;                    // bf16 full / f32 half
  constexpr int SMEM_B = STAGE_B > EPI_B ? STAGE_B : EPI_B;
  __shared__ __align__(16) char smem[SMEM_B];
  u16* lA = (u16*)smem;
  u16* lB = (u16*)(smem + BM * 128);

  const int tid = threadIdx.x;
  const int lane = tid & 63, wid = tid >> 6;
  const int wm = wid >> 1, wn = wid & 1;                // 2x2 wave grid
  constexpr int FM = BM / 32, FN = 4;
  constexpr int ITA = BM / 32, ITB = BN / 32;           // gload_lds per wave

  // bijective XCD swizzle (m204), then M-fastest decomposition
  const int nwg = gridDim.x;
  const int q = nwg >> 3, r8 = nwg & 7;
  const int xcd = blockIdx.x & 7, idx = blockIdx.x >> 3;
  const int wgid = (xcd < r8 ? xcd * (q + 1) : r8 * (q + 1) + (xcd - r8) * q) + idx;
  const int tileM = (wgid % gridM) * BM, tileN = (wgid / gridM) * BN;

  f32x4 acc[FM][FN] = {};

  const int kSteps = K >> 6;
  for (int kt = 0; kt < kSteps; ++kt) {
    __syncthreads();  // previous iteration's readers done
#pragma unroll
    for (int it = 0; it < ITA; ++it) {
      int ch = (wid * ITA + it) * 64 + lane;            // linear 16B chunk
      int row = ch >> 3, slot = ch & 7;
      int grow = tileM + row; grow = grow < M ? grow : (M - 1);
      async_copy16(A + (size_t)grow * K + kt * 64 + ((slot ^ (row & 7)) << 3),
                   smem + (wid * ITA + it) * 1024);
    }
#pragma unroll
    for (int it = 0; it < ITB; ++it) {
      int ch = (wid * ITB + it) * 64 + lane;
      int row = ch >> 3, slot = ch & 7;
      async_copy16(Bt + (size_t)(tileN + row) * K + kt * 64 + ((slot ^ (row & 7)) << 3),
                   smem + BM * 128 + (wid * ITB + it) * 1024);
    }
    __syncthreads();  // compiler drains vmcnt before barrier

#pragma unroll
    for (int kk = 0; kk < 2; ++kk) {
      const int j = kk * 4 + (lane >> 4);               // logical k-chunk
      bf16x8v af[FM], bfr[FN];
#pragma unroll
      for (int fm = 0; fm < FM; ++fm) {
        int rr = wm * (BM / 2) + fm * 16 + (lane & 15);
        af[fm] = *(const bf16x8v*)(lA + rr * 64 + ((j ^ (rr & 7)) << 3));
      }
#pragma unroll
      for (int fn = 0; fn < FN; ++fn) {
        int rn = wn * 64 + fn * 16 + (lane & 15);
        bfr[fn] = *(const bf16x8v*)(lB + rn * 64 + ((j ^ (rn & 7)) << 3));
      }
#pragma unroll
      for (int fm = 0; fm < FM; ++fm)
#pragma unroll
        for (int fn = 0; fn < FN; ++fn)
          acc[fm][fn] = __builtin_amdgcn_mfma_f32_16x16x32_bf16(
              af[fm], bfr[fn], acc[fm][fn], 0, 0, 0);
    }
  }

  const int fla = (EPI == 0) ? 0 : *fl;
  const int row0l = wm * (BM / 2);
  const int col0l = wn * 64;

  // bf16 output: full-tile u16 LDS stage, 16B-chunk coalesced writes.
  auto store_bf16 = [&](bool do_bias, bool do_gelu) {
    u16* ep = (u16*)smem;
    __syncthreads();
#pragma unroll
    for (int fm = 0; fm < FM; ++fm)
#pragma unroll
      for (int fn = 0; fn < FN; ++fn)
#pragma unroll
        for (int jj = 0; jj < 4; ++jj) {
          int rl = row0l + fm * 16 + ((lane >> 4) << 2) + jj;
          int cl = col0l + fn * 16 + (lane & 15);
          float t = acc[fm][fn][jj];
          if (do_bias) t += ld_f(bias, boff + tileN + cl, fla);
          if (do_gelu) t = 0.5f * t * (1.0f + erff(t * 0.70710678118654752f));
          ep[rl * BN + cl] = f2bf(t);
        }
    __syncthreads();
    for (int rr = tid >> 4; rr < BM; rr += 16) {
      int grow = tileM + rr;
      if (grow < M)
        *(uint4*)((u16*)Cout + (size_t)grow * N + tileN + (tid & 15) * 8) =
            *(const uint4*)(ep + rr * BN + (tid & 15) * 8);
    }
  };

  // f32 output: two half-tile LDS passes, f32x4 coalesced writes.
  auto store_f32 = [&](bool do_resid, bool do_remap_pos) {
    float* epf = (float*)smem;
#pragma unroll
    for (int p = 0; p < 2; ++p) {
      __syncthreads();
      if (wm == p) {
#pragma unroll
        for (int fm = 0; fm < FM; ++fm)
#pragma unroll
          for (int fn = 0; fn < FN; ++fn)
#pragma unroll
            for (int jj = 0; jj < 4; ++jj) {
              int rl = fm * 16 + ((lane >> 4) << 2) + jj;
              int cl = col0l + fn * 16 + (lane & 15);
              float t = acc[fm][fn][jj] + ld_f(bias, boff + tileN + cl, fla);
              if (do_remap_pos) {
                int grow_t = tileM + p * (BM / 2) + rl;
                int ll = grow_t % 49;
                t += ld_f(pos, ll * 512 + tileN + cl, fla);
              }
              epf[rl * BN + cl] = t;
            }
      }
      __syncthreads();
      for (int rr = tid >> 5; rr < BM / 2; rr += 8) {
        int grow = tileM + p * (BM / 2) + rr;
        if (grow < M) {
          f32x4 t = *(const f32x4*)(epf + rr * BN + (tid & 31) * 4);
          if (do_resid)
            t += *(const f32x4*)(resid + (size_t)grow * N + tileN + (tid & 31) * 4);
          size_t orow = grow;
          if (do_remap_pos) orow = (size_t)(grow / 49) * 126 + grow % 49;
          *(f32x4*)((float*)Cout + orow * N + tileN + (tid & 31) * 4) = t;
        }
      }
    }
  };

  if constexpr (EPI == 0) store_bf16(false, false);
  else if constexpr (EPI == 1) store_bf16(true, true);
  else if constexpr (EPI == 2) store_f32(true, false);
  else if constexpr (EPI == 3) store_f32(false, true);
  else { if (fla) store_f32(false, false); else store_bf16(true, false); }
}

// 32x32 tiled transpose: in [R][C] (flag dtype, z-batched) -> out [C][R] bf16.
__global__ __launch_bounds__(256) void transpose_any(
    const void* __restrict__ in, u16* __restrict__ out, int R, int C,
    const int* __restrict__ fl)
{
  const int fla = *fl;
  __shared__ u16 t[32][33];
  const size_t zo = (size_t)blockIdx.z * R * C;
  const int c0 = blockIdx.x * 32, r0 = blockIdx.y * 32;
  const int tx = threadIdx.x & 31, ty = threadIdx.x >> 5;
#pragma unroll
  for (int i = 0; i < 4; ++i)
    t[ty + 8 * i][tx] = ld_bf(in, zo + (size_t)(r0 + ty + 8 * i) * C + (c0 + tx), fla);
  __syncthreads();
#pragma unroll
  for (int i = 0; i < 4; ++i)
    out[zo + (size_t)(c0 + ty + 8 * i) * R + (r0 + tx)] = t[tx][ty + 8 * i];
}

// wq/wk/wv [4][8][512][64] -> qkvT [4][1536][512], head h rows at h*64+obase.
__global__ __launch_bounds__(256) void transpose_qkv(
    const void* __restrict__ in, u16* __restrict__ out, int obase,
    const int* __restrict__ fl)
{
  const int fla = *fl;
  __shared__ u16 t[32][33];
  const int z = blockIdx.z, li = z >> 3, hh = z & 7;
  const size_t zi = (size_t)z * 512 * 64;
  const size_t zo = (size_t)li * (1536 * 512) + (size_t)(obase + hh * 64) * 512;
  const int c0 = blockIdx.x * 32, r0 = blockIdx.y * 32;
  const int tx = threadIdx.x & 31, ty = threadIdx.x >> 5;
#pragma unroll
  for (int i = 0; i < 4; ++i)
    t[ty + 8 * i][tx] = ld_bf(in, zi + (size_t)(r0 + ty + 8 * i) * 64 + (c0 + tx), fla);
  __syncthreads();
#pragma unroll
  for (int i = 0; i < 4; ++i)
    out[zo + (size_t)(c0 + ty + 8 * i) * 512 + (r0 + tx)] = t[tx][ty + 8 * i];
}

// Attention: one block per (b, h, row-half). qkv packed [B*L][1536].
__global__ __launch_bounds__(256) void attn_kernel(
    const u16* __restrict__ qkv, const int* __restrict__ amask,
    u16* __restrict__ o)
{
  const int b = blockIdx.x, hh = blockIdx.y, half = blockIdx.z;
  __shared__ float Kf[126 * 65];
  __shared__ u16 Vh[126 * 65];
  __shared__ float P[4][128];
  __shared__ float padK[128];
  const int tid = threadIdx.x, lane = tid & 63, wid = tid >> 6;

  for (int idx = tid; idx < 126 * 64; idx += 256) {
    int m = idx >> 6, kk = idx & 63;
    size_t base = ((size_t)(b * 126 + m)) * 1536 + hh * 64 + kk;
    Kf[m * 65 + kk] = bf2f(qkv[base + 512]);
    Vh[m * 65 + kk] = qkv[base + 1024];
  }
  for (int j = tid; j < 128; j += 256) {
    float kv = 0.0f;
    if (j < 49) kv = 1.0f;
    else if (j < 126) kv = (amask[b * 77 + (j - 49)] != 0) ? 1.0f : 0.0f;
    padK[j] = kv;
  }
  __syncthreads();

  const float scale = 0.04419417382415922f;  // 512^-0.5 (full-D, faithful)
  const int lbase = half * 63;
  for (int l = lbase + wid; l < lbase + 63; l += 4) {
    float qv = bf2f(qkv[((size_t)(b * 126 + l)) * 1536 + hh * 64 + lane]);
    const int m0 = lane;
    const int m1v = lane + 64;
    const int m1 = m1v < 126 ? m1v : 125;
    const float* K0 = Kf + m0 * 65;
    const float* K1 = Kf + m1 * 65;
    float s0 = 0.f, s1 = 0.f;
#pragma unroll 8
    for (int kk = 0; kk < 64; ++kk) {
      float qs = __shfl(qv, kk, 64);
      s0 += qs * K0[kk];
      s1 += qs * K1[kk];
    }
    s0 *= scale; s1 *= scale;
    bool kp0 = (padK[m0] != 0.f) && (m0 < 49 || l < 49 || m0 <= l);
    bool kp1 = (padK[m1v] != 0.f) && (l < 49 || m1v <= l);
    float e0 = kp0 ? s0 : -1e30f;
    float e1 = kp1 ? s1 : -1e30f;
    float mx = fmaxf(e0, e1);
#pragma unroll
    for (int off = 32; off; off >>= 1) mx = fmaxf(mx, __shfl_xor(mx, off, 64));
    float p0 = kp0 ? __expf(s0 - mx) : 0.f;
    float p1 = kp1 ? __expf(s1 - mx) : 0.f;
    float sm = p0 + p1;
#pragma unroll
    for (int off = 32; off; off >>= 1) sm += __shfl_xor(sm, off, 64);
    float inv = 1.0f / sm;
    P[wid][lane] = p0 * inv;
    P[wid][lane + 64] = p1 * inv;
    float accv = 0.f;
#pragma unroll 6
    for (int m = 0; m < 126; ++m) accv += P[wid][m] * bf2f(Vh[m * 65 + lane]);
    o[((size_t)(b * 126 + l)) * 512 + hh * 64 + lane] = f2bf(accv);
  }
}

// LayerNorm over D=512 (x f32 -> bf16). goff = element offset into gam/bet.
template <int REMAP>
__global__ __launch_bounds__(256) void ln_kernel(
    const float* __restrict__ x, const void* __restrict__ gam,
    const void* __restrict__ bet, long goff, u16* __restrict__ out,
    const int* __restrict__ fl)
{
  const int fla = *fl;
  const int r = blockIdx.x;
  int srow, drow;
  if constexpr (REMAP) { int bb = r / 77, t = r % 77; srow = bb * 126 + 49 + t; drow = r; }
  else { srow = r; drow = r; }
  const float* xr = x + (size_t)srow * 512;
  const int tid = threadIdx.x, lane = tid & 63, wid = tid >> 6;
  float a = xr[tid], c = xr[tid + 256];
  float s = a + c;
#pragma unroll
  for (int off = 32; off; off >>= 1) s += __shfl_xor(s, off, 64);
  __shared__ float red0[4], red1[4];
  if (lane == 0) red0[wid] = s;
  __syncthreads();
  float mu = (red0[0] + red0[1] + red0[2] + red0[3]) * (1.0f / 512.0f);
  float da = a - mu, dc = c - mu;
  float q2 = da * da + dc * dc;
#pragma unroll
  for (int off = 32; off; off >>= 1) q2 += __shfl_xor(q2, off, 64);
  if (lane == 0) red1[wid] = q2;
  __syncthreads();
  float var = (red1[0] + red1[1] + red1[2] + red1[3]) * (1.0f / 512.0f);
  float inv = rsqrtf(var + 1e-5f);
  u16* orow = out + (size_t)drow * 512;
  orow[tid] = f2bf(da * inv * ld_f(gam, goff + tid, fla) + ld_f(bet, goff + tid, fla));
  orow[tid + 256] =
      f2bf(dc * inv * ld_f(gam, goff + tid + 256, fla) + ld_f(bet, goff + tid + 256, fla));
}

__global__ __launch_bounds__(256) void txt_embed_kernel(
    const void* __restrict__ txt, const void* __restrict__ pos,
    float* __restrict__ x, const int* __restrict__ fl)
{
  const int fla = *fl;
  int idx = blockIdx.x * 256 + threadIdx.x;
  if (idx < 32 * 77 * 512) {
    int d = idx & 511;
    int bt = idx >> 9;
    int t = bt % 77, bb = bt / 77;
    x[((size_t)(bb * 126 + 49 + t)) * 512 + d] =
        ld_f(txt, idx, fla) + ld_f(pos, (49 + t) * 512 + d, fla);
  }
}

// ---------------------------------------------------------------------------
extern "C" void kernel_launch(void* const* d_in, const int* in_sizes, int n_in,
                              void* d_out, int out_size, void* d_ws, size_t ws_size,
                              hipStream_t stream)
{
  (void)in_sizes; (void)n_in; (void)out_size;
  const void* img_hidden = d_in[0];
  const void* txt_emb    = d_in[1];
  const void* img_proj_w = d_in[2];
  const void* img_proj_b = d_in[3];
  const void* pos_embed  = d_in[4];
  const void* wq    = d_in[5];
  const void* wk    = d_in[6];
  const void* wv    = d_in[7];
  const void* w_proj = d_in[8];
  const void* b_proj = d_in[9];
  const void* ln1_g = d_in[10];
  const void* ln1_b = d_in[11];
  const void* ln2_g = d_in[12];
  const void* ln2_b = d_in[13];
  const void* fc1_w = d_in[14];
  const void* fc1_b = d_in[15];
  const void* fc2_w = d_in[16];
  const void* fc2_b = d_in[17];
  const void* lnf_g = d_in[18];
  const void* lnf_b = d_in[19];
  const void* out_w = d_in[20];
  const void* out_b = d_in[21];
  const int* amask  = (const int*)d_in[22];

  char* ws = (char*)d_ws;
  size_t off = 0;
  auto alloc = [&](size_t bytes) {
    void* p = ws + off; off += (bytes + 255) & ~(size_t)255; return p;
  };
  int* dflag = (int*)alloc(256);
  u16* imgbf = (u16*)alloc(1204224ull * 2);
  float* x   = (float*)alloc(4032ull * 512 * 4);
  u16* xl    = (u16*)alloc(2464ull * 512 * 2);
  const size_t uni0 = off;
  u16* imgwT = (u16*)alloc(512ull * 768 * 2);
  u16* qkvT  = (u16*)alloc(4ull * 1536 * 512 * 2);
  u16* wpT   = (u16*)alloc(4ull * 512 * 512 * 2);
  u16* fc1T  = (u16*)alloc(4ull * 2048 * 512 * 2);
  u16* fc2T  = (u16*)alloc(4ull * 512 * 2048 * 2);
  u16* h     = (u16*)alloc(4032ull * 512 * 2);
  u16* qkvb  = (u16*)alloc(4032ull * 1536 * 2);
  u16* ob    = (u16*)alloc(4032ull * 512 * 2);
  u16* ff    = (u16*)alloc(4032ull * 2048 * 2);
  u16* outwT = (u16*)(ws + uni0);   // 50.6 MB, aliases dead loop buffers

  if (ws_size < off) {
    sentinel_kernel<<<dim3(16), 256, 0, stream>>>((float*)d_out);
    return;
  }

  detect_kernel<<<dim3(1), 64, 0, stream>>>(img_hidden, dflag);
  convert_kernel<<<dim3(4704), 256, 0, stream>>>(img_hidden, imgbf, 1204224, dflag);

  transpose_any<<<dim3(16, 24, 1), 256, 0, stream>>>(img_proj_w, imgwT, 768, 512, dflag);
  transpose_qkv<<<dim3(2, 16, 32), 256, 0, stream>>>(wq, qkvT, 0, dflag);
  transpose_qkv<<<dim3(2, 16, 32), 256, 0, stream>>>(wk, qkvT, 512, dflag);
  transpose_qkv<<<dim3(2, 16, 32), 256, 0, stream>>>(wv, qkvT, 1024, dflag);
  transpose_any<<<dim3(16, 16, 4), 256, 0, stream>>>(w_proj, wpT, 512, 512, dflag);
  transpose_any<<<dim3(64, 16, 4), 256, 0, stream>>>(fc1_w, fc1T, 512, 2048, dflag);
  transpose_any<<<dim3(16, 64, 4), 256, 0, stream>>>(fc2_w, fc2T, 2048, 512, dflag);

  gemm_kernel<64, 128, 3><<<dim3(100), 256, 0, stream>>>(
      imgbf, imgwT, x, img_proj_b, 0, nullptr, pos_embed, 1568, 512, 768, 25, dflag);
  txt_embed_kernel<<<dim3(4928), 256, 0, stream>>>(txt_emb, pos_embed, x, dflag);

  for (int i = 0; i < 4; ++i) {
    ln_kernel<0><<<dim3(4032), 256, 0, stream>>>(x, ln1_g, ln1_b, i * 512, h, dflag);
    gemm_kernel<64, 128, 0><<<dim3(756), 256, 0, stream>>>(
        h, qkvT + i * 786432, qkvb, nullptr, 0, nullptr, nullptr, 4032, 1536, 512, 63, dflag);
    attn_kernel<<<dim3(32, 8, 2), 256, 0, stream>>>(qkvb, amask, ob);
    gemm_kernel<64, 128, 2><<<dim3(252), 256, 0, stream>>>(
        ob, wpT + i * 262144, x, b_proj, i * 512, x, nullptr, 4032, 512, 512, 63, dflag);
    ln_kernel<0><<<dim3(4032), 256, 0, stream>>>(x, ln2_g, ln2_b, i * 512, h, dflag);
    gemm_kernel<64, 128, 1><<<dim3(1008), 256, 0, stream>>>(
        h, fc1T + i * 1048576, ff, fc1_b, i * 2048, nullptr, nullptr, 4032, 2048, 512, 63, dflag);
    gemm_kernel<64, 128, 2><<<dim3(252), 256, 0, stream>>>(
        ff, fc2T + i * 1048576, x, fc2_b, i * 512, x, nullptr, 4032, 512, 2048, 63, dflag);
  }

  ln_kernel<1><<<dim3(2464), 256, 0, stream>>>(x, lnf_g, lnf_b, 0, xl, dflag);
  transpose_any<<<dim3(1544, 16, 1), 256, 0, stream>>>(out_w, outwT, 512, 49408, dflag);
  gemm_kernel<128, 128, 4><<<dim3(7720), 256, 0, stream>>>(
      xl, outwT, d_out, out_b, 0, nullptr, nullptr, 2464, 49408, 512, 20, dflag);
}

// Round 6
// 1062.477 us; speedup vs baseline: 1.5082x; 1.0433x over previous
//
#include <hip/hip_runtime.h>
#include <hip/hip_bf16.h>
#include <stdint.h>

// ---------------------------------------------------------------------------
// MMTransformer: B=32, IMG_LEN=49, TXT_LEN=77, L=126, D=512, H=8, HK=64,
// FF=2048, NB=4, IMG_DIM=768, VOCAB=49408.
// Round 5: minimum-2-phase pipelined GEMM (T3 recipe): double-buffered LDS,
// stage(next) issued BEFORE compute(cur), ONE barrier per K-step whose
// implicit vmcnt(0) drain lands after compute has hidden the load latency.
// Retained: BK=64, both-sides chunk-XOR LDS swizzle, bijective XCD swizzle,
// LDS-coalesced epilogues, runtime input-dtype detection.
// ---------------------------------------------------------------------------

using u16 = unsigned short;
typedef __attribute__((ext_vector_type(8))) __bf16 bf16x8v;
typedef __attribute__((ext_vector_type(4))) float f32x4;

__device__ __forceinline__ float bf2f(u16 u) {
  union { unsigned int i; float f; } x; x.i = ((unsigned int)u) << 16; return x.f;
}
__device__ __forceinline__ u16 f2bf(float f) {
  union { float f; unsigned int i; } u; u.f = f;
  unsigned int r = u.i + 0x7FFFu + ((u.i >> 16) & 1u);   // RNE
  return (u16)(r >> 16);
}
__device__ __forceinline__ float ld_f(const void* p, size_t i, int fl) {
  return fl ? ((const float*)p)[i] : bf2f(((const u16*)p)[i]);
}
__device__ __forceinline__ u16 ld_bf(const void* p, size_t i, int fl) {
  return fl ? f2bf(((const float*)p)[i]) : ((const u16*)p)[i];
}

// async global->LDS, 16B per lane; LDS dest = wave-uniform base + lane*16.
__device__ __forceinline__ void async_copy16(const void* g, void* l) {
  __builtin_amdgcn_global_load_lds(
      (__attribute__((address_space(1))) void*)(g),
      (__attribute__((address_space(3))) void*)(l), 16, 0, 0);
}

// dtype detector: img_hidden ~ N(0,1). bf16 buffer -> ~0 implausible u16s;
// f32 buffer -> even-index u16s are mantissa bits, ~50-60% implausible.
__global__ void detect_kernel(const void* __restrict__ img, int* __restrict__ flag) {
  const int lane = threadIdx.x;
  const u16* p = (const u16*)img;
  int bad = 0;
#pragma unroll
  for (int i = 0; i < 4; ++i) {
    float v = bf2f(p[lane * 4 + i]);
    float av = fabsf(v);
    if (!(av <= 1e4f) || (av != 0.0f && av < 1e-30f)) bad++;
  }
#pragma unroll
  for (int off = 32; off; off >>= 1) bad += __shfl_xor(bad, off, 64);
  if (lane == 0) flag[0] = (bad > 16) ? 1 : 0;
}

__global__ void sentinel_kernel(float* out) {
  out[blockIdx.x * 256 + threadIdx.x] = 123456.0f;
}

__global__ __launch_bounds__(256) void convert_kernel(
    const void* __restrict__ in, u16* __restrict__ out, int n,
    const int* __restrict__ fl) {
  const int fla = *fl;
  int i = blockIdx.x * 256 + threadIdx.x;
  if (i < n) out[i] = ld_bf(in, i, fla);
}

// ---------------------------------------------------------------------------
// bf16 MFMA GEMM: C[M,N] = A[M,K] @ Bt[N,K]^T (+ epilogue). BN=128, BK=64.
// 2-phase pipeline: dbuf LDS, prefetch next K-tile before computing current,
// single __syncthreads per step (implicit vmcnt/lgkm drain after compute).
// LDS tiles [rows][64] bf16, 16B-chunk XOR swizzle both sides.
// 1D grid, bijective XCD swizzle, M-fastest within XCD.
// EPI 0: bf16 (no bias). EPI 1: gelu(acc+bias) bf16. EPI 2: acc+bias+resid
// f32. EPI 3: img embed f32 (+pos, row remap). EPI 4: acc+bias -> d_out.
// ---------------------------------------------------------------------------
template <int BM, int BN, int EPI>
__global__ __launch_bounds__(256) void gemm_kernel(
    const u16* __restrict__ A, const u16* __restrict__ Bt, void* Cout,
    const void* __restrict__ bias, long boff, const float* resid,
    const void* __restrict__ pos, int M, int N, int K, int gridM,
    const int* __restrict__ fl)
{
  static_assert(BN == 128, "");
  static_assert(BM == 64 || BM == 128, "");
  constexpr int TILE_B = (BM + BN) * 128;               // bytes per K-tile buf
  constexpr int EPI_B = BM * BN * 2;
  constexpr int SMEM_B = (2 * TILE_B > EPI_B) ? 2 * TILE_B : EPI_B;
  __shared__ __align__(16) char smem[SMEM_B];

  const int tid = threadIdx.x;
  const int lane = tid & 63, wid = tid >> 6;
  const int wm = wid >> 1, wn = wid & 1;                // 2x2 wave grid
  constexpr int FM = BM / 32, FN = 4;
  constexpr int ITA = BM / 32, ITB = BN / 32;           // gload_lds per wave

  // bijective XCD swizzle (m204), then M-fastest decomposition
  const int nwg = gridDim.x;
  const int q = nwg >> 3, r8 = nwg & 7;
  const int xcd = blockIdx.x & 7, idx = blockIdx.x >> 3;
  const int wgid = (xcd < r8 ? xcd * (q + 1) : r8 * (q + 1) + (xcd - r8) * q) + idx;
  const int tileM = (wgid % gridM) * BM, tileN = (wgid / gridM) * BN;

  f32x4 acc[FM][FN] = {};

  auto stage = [&](int buf, int kt) {
    char* base = smem + buf * TILE_B;
#pragma unroll
    for (int it = 0; it < ITA; ++it) {
      int ch = (wid * ITA + it) * 64 + lane;            // linear 16B chunk
      int row = ch >> 3, slot = ch & 7;
      int grow = tileM + row; grow = grow < M ? grow : (M - 1);
      async_copy16(A + (size_t)grow * K + kt * 64 + ((slot ^ (row & 7)) << 3),
                   base + (wid * ITA + it) * 1024);
    }
#pragma unroll
    for (int it = 0; it < ITB; ++it) {
      int ch = (wid * ITB + it) * 64 + lane;
      int row = ch >> 3, slot = ch & 7;
      async_copy16(Bt + (size_t)(tileN + row) * K + kt * 64 + ((slot ^ (row & 7)) << 3),
                   base + BM * 128 + (wid * ITB + it) * 1024);
    }
  };

  const int kSteps = K >> 6;
  stage(0, 0);
  __syncthreads();                       // drains vmcnt(0): buf0 ready
  int cur = 0;
  for (int kt = 0; kt < kSteps; ++kt) {
    if (kt + 1 < kSteps) stage(cur ^ 1, kt + 1);   // prefetch next K-tile
    const u16* lA = (const u16*)(smem + cur * TILE_B);
    const u16* lB = (const u16*)(smem + cur * TILE_B + BM * 128);
#pragma unroll
    for (int kk = 0; kk < 2; ++kk) {
      const int j = kk * 4 + (lane >> 4);             // logical k-chunk
      bf16x8v af[FM], bfr[FN];
#pragma unroll
      for (int fm = 0; fm < FM; ++fm) {
        int rr = wm * (BM / 2) + fm * 16 + (lane & 15);
        af[fm] = *(const bf16x8v*)(lA + rr * 64 + ((j ^ (rr & 7)) << 3));
      }
#pragma unroll
      for (int fn = 0; fn < FN; ++fn) {
        int rn = wn * 64 + fn * 16 + (lane & 15);
        bfr[fn] = *(const bf16x8v*)(lB + rn * 64 + ((j ^ (rn & 7)) << 3));
      }
#pragma unroll
      for (int fm = 0; fm < FM; ++fm)
#pragma unroll
        for (int fn = 0; fn < FN; ++fn)
          acc[fm][fn] = __builtin_amdgcn_mfma_f32_16x16x32_bf16(
              af[fm], bfr[fn], acc[fm][fn], 0, 0, 0);
    }
    __syncthreads();                     // readers done + next buf ready
    cur ^= 1;
  }

  const int fla = (EPI == 0) ? 0 : *fl;
  const int row0l = wm * (BM / 2);
  const int col0l = wn * 64;

  // bf16 output: full-tile u16 LDS stage, 16B-chunk coalesced writes.
  auto store_bf16 = [&](bool do_bias, bool do_gelu) {
    u16* ep = (u16*)smem;
#pragma unroll
    for (int fm = 0; fm < FM; ++fm)
#pragma unroll
      for (int fn = 0; fn < FN; ++fn)
#pragma unroll
        for (int jj = 0; jj < 4; ++jj) {
          int rl = row0l + fm * 16 + ((lane >> 4) << 2) + jj;
          int cl = col0l + fn * 16 + (lane & 15);
          float t = acc[fm][fn][jj];
          if (do_bias) t += ld_f(bias, boff + tileN + cl, fla);
          if (do_gelu) t = 0.5f * t * (1.0f + erff(t * 0.70710678118654752f));
          ep[rl * BN + cl] = f2bf(t);
        }
    __syncthreads();
    for (int rr = tid >> 4; rr < BM; rr += 16) {
      int grow = tileM + rr;
      if (grow < M)
        *(uint4*)((u16*)Cout + (size_t)grow * N + tileN + (tid & 15) * 8) =
            *(const uint4*)(ep + rr * BN + (tid & 15) * 8);
    }
  };

  // f32 output: two half-tile LDS passes, f32x4 coalesced writes.
  auto store_f32 = [&](bool do_resid, bool do_remap_pos) {
    float* epf = (float*)smem;
#pragma unroll
    for (int p = 0; p < 2; ++p) {
      __syncthreads();
      if (wm == p) {
#pragma unroll
        for (int fm = 0; fm < FM; ++fm)
#pragma unroll
          for (int fn = 0; fn < FN; ++fn)
#pragma unroll
            for (int jj = 0; jj < 4; ++jj) {
              int rl = fm * 16 + ((lane >> 4) << 2) + jj;
              int cl = col0l + fn * 16 + (lane & 15);
              float t = acc[fm][fn][jj] + ld_f(bias, boff + tileN + cl, fla);
              if (do_remap_pos) {
                int grow_t = tileM + p * (BM / 2) + rl;
                int ll = grow_t % 49;
                t += ld_f(pos, ll * 512 + tileN + cl, fla);
              }
              epf[rl * BN + cl] = t;
            }
      }
      __syncthreads();
      for (int rr = tid >> 5; rr < BM / 2; rr += 8) {
        int grow = tileM + p * (BM / 2) + rr;
        if (grow < M) {
          f32x4 t = *(const f32x4*)(epf + rr * BN + (tid & 31) * 4);
          if (do_resid)
            t += *(const f32x4*)(resid + (size_t)grow * N + tileN + (tid & 31) * 4);
          size_t orow = grow;
          if (do_remap_pos) orow = (size_t)(grow / 49) * 126 + grow % 49;
          *(f32x4*)((float*)Cout + orow * N + tileN + (tid & 31) * 4) = t;
        }
      }
    }
  };

  if constexpr (EPI == 0) store_bf16(false, false);
  else if constexpr (EPI == 1) store_bf16(true, true);
  else if constexpr (EPI == 2) store_f32(true, false);
  else if constexpr (EPI == 3) store_f32(false, true);
  else { if (fla) store_f32(false, false); else store_bf16(true, false); }
}

// 32x32 tiled transpose: in [R][C] (flag dtype, z-batched) -> out [C][R] bf16.
__global__ __launch_bounds__(256) void transpose_any(
    const void* __restrict__ in, u16* __restrict__ out, int R, int C,
    const int* __restrict__ fl)
{
  const int fla = *fl;
  __shared__ u16 t[32][33];
  const size_t zo = (size_t)blockIdx.z * R * C;
  const int c0 = blockIdx.x * 32, r0 = blockIdx.y * 32;
  const int tx = threadIdx.x & 31, ty = threadIdx.x >> 5;
#pragma unroll
  for (int i = 0; i < 4; ++i)
    t[ty + 8 * i][tx] = ld_bf(in, zo + (size_t)(r0 + ty + 8 * i) * C + (c0 + tx), fla);
  __syncthreads();
#pragma unroll
  for (int i = 0; i < 4; ++i)
    out[zo + (size_t)(c0 + ty + 8 * i) * R + (r0 + tx)] = t[tx][ty + 8 * i];
}

// wq/wk/wv [4][8][512][64] -> qkvT [4][1536][512], head h rows at h*64+obase.
__global__ __launch_bounds__(256) void transpose_qkv(
    const void* __restrict__ in, u16* __restrict__ out, int obase,
    const int* __restrict__ fl)
{
  const int fla = *fl;
  __shared__ u16 t[32][33];
  const int z = blockIdx.z, li = z >> 3, hh = z & 7;
  const size_t zi = (size_t)z * 512 * 64;
  const size_t zo = (size_t)li * (1536 * 512) + (size_t)(obase + hh * 64) * 512;
  const int c0 = blockIdx.x * 32, r0 = blockIdx.y * 32;
  const int tx = threadIdx.x & 31, ty = threadIdx.x >> 5;
#pragma unroll
  for (int i = 0; i < 4; ++i)
    t[ty + 8 * i][tx] = ld_bf(in, zi + (size_t)(r0 + ty + 8 * i) * 64 + (c0 + tx), fla);
  __syncthreads();
#pragma unroll
  for (int i = 0; i < 4; ++i)
    out[zo + (size_t)(c0 + ty + 8 * i) * 512 + (r0 + tx)] = t[tx][ty + 8 * i];
}

// Attention: one block per (b, h, row-half). qkv packed [B*L][1536].
__global__ __launch_bounds__(256) void attn_kernel(
    const u16* __restrict__ qkv, const int* __restrict__ amask,
    u16* __restrict__ o)
{
  const int b = blockIdx.x, hh = blockIdx.y, half = blockIdx.z;
  __shared__ float Kf[126 * 65];
  __shared__ u16 Vh[126 * 65];
  __shared__ float P[4][128];
  __shared__ float padK[128];
  const int tid = threadIdx.x, lane = tid & 63, wid = tid >> 6;

  for (int idx = tid; idx < 126 * 64; idx += 256) {
    int m = idx >> 6, kk = idx & 63;
    size_t base = ((size_t)(b * 126 + m)) * 1536 + hh * 64 + kk;
    Kf[m * 65 + kk] = bf2f(qkv[base + 512]);
    Vh[m * 65 + kk] = qkv[base + 1024];
  }
  for (int j = tid; j < 128; j += 256) {
    float kv = 0.0f;
    if (j < 49) kv = 1.0f;
    else if (j < 126) kv = (amask[b * 77 + (j - 49)] != 0) ? 1.0f : 0.0f;
    padK[j] = kv;
  }
  __syncthreads();

  const float scale = 0.04419417382415922f;  // 512^-0.5 (full-D, faithful)
  const int lbase = half * 63;
  for (int l = lbase + wid; l < lbase + 63; l += 4) {
    float qv = bf2f(qkv[((size_t)(b * 126 + l)) * 1536 + hh * 64 + lane]);
    const int m0 = lane;
    const int m1v = lane + 64;
    const int m1 = m1v < 126 ? m1v : 125;
    const float* K0 = Kf + m0 * 65;
    const float* K1 = Kf + m1 * 65;
    float s0 = 0.f, s1 = 0.f;
#pragma unroll 8
    for (int kk = 0; kk < 64; ++kk) {
      float qs = __shfl(qv, kk, 64);
      s0 += qs * K0[kk];
      s1 += qs * K1[kk];
    }
    s0 *= scale; s1 *= scale;
    bool kp0 = (padK[m0] != 0.f) && (m0 < 49 || l < 49 || m0 <= l);
    bool kp1 = (padK[m1v] != 0.f) && (l < 49 || m1v <= l);
    float e0 = kp0 ? s0 : -1e30f;
    float e1 = kp1 ? s1 : -1e30f;
    float mx = fmaxf(e0, e1);
#pragma unroll
    for (int off = 32; off; off >>= 1) mx = fmaxf(mx, __shfl_xor(mx, off, 64));
    float p0 = kp0 ? __expf(s0 - mx) : 0.f;
    float p1 = kp1 ? __expf(s1 - mx) : 0.f;
    float sm = p0 + p1;
#pragma unroll
    for (int off = 32; off; off >>= 1) sm += __shfl_xor(sm, off, 64);
    float inv = 1.0f / sm;
    P[wid][lane] = p0 * inv;
    P[wid][lane + 64] = p1 * inv;
    float accv = 0.f;
#pragma unroll 6
    for (int m = 0; m < 126; ++m) accv += P[wid][m] * bf2f(Vh[m * 65 + lane]);
    o[((size_t)(b * 126 + l)) * 512 + hh * 64 + lane] = f2bf(accv);
  }
}

// LayerNorm over D=512 (x f32 -> bf16). goff = element offset into gam/bet.
template <int REMAP>
__global__ __launch_bounds__(256) void ln_kernel(
    const float* __restrict__ x, const void* __restrict__ gam,
    const void* __restrict__ bet, long goff, u16* __restrict__ out,
    const int* __restrict__ fl)
{
  const int fla = *fl;
  const int r = blockIdx.x;
  int srow, drow;
  if constexpr (REMAP) { int bb = r / 77, t = r % 77; srow = bb * 126 + 49 + t; drow = r; }
  else { srow = r; drow = r; }
  const float* xr = x + (size_t)srow * 512;
  const int tid = threadIdx.x, lane = tid & 63, wid = tid >> 6;
  float a = xr[tid], c = xr[tid + 256];
  float s = a + c;
#pragma unroll
  for (int off = 32; off; off >>= 1) s += __shfl_xor(s, off, 64);
  __shared__ float red0[4], red1[4];
  if (lane == 0) red0[wid] = s;
  __syncthreads();
  float mu = (red0[0] + red0[1] + red0[2] + red0[3]) * (1.0f / 512.0f);
  float da = a - mu, dc = c - mu;
  float q2 = da * da + dc * dc;
#pragma unroll
  for (int off = 32; off; off >>= 1) q2 += __shfl_xor(q2, off, 64);
  if (lane == 0) red1[wid] = q2;
  __syncthreads();
  float var = (red1[0] + red1[1] + red1[2] + red1[3]) * (1.0f / 512.0f);
  float inv = rsqrtf(var + 1e-5f);
  u16* orow = out + (size_t)drow * 512;
  orow[tid] = f2bf(da * inv * ld_f(gam, goff + tid, fla) + ld_f(bet, goff + tid, fla));
  orow[tid + 256] =
      f2bf(dc * inv * ld_f(gam, goff + tid + 256, fla) + ld_f(bet, goff + tid + 256, fla));
}

__global__ __launch_bounds__(256) void txt_embed_kernel(
    const void* __restrict__ txt, const void* __restrict__ pos,
    float* __restrict__ x, const int* __restrict__ fl)
{
  const int fla = *fl;
  int idx = blockIdx.x * 256 + threadIdx.x;
  if (idx < 32 * 77 * 512) {
    int d = idx & 511;
    int bt = idx >> 9;
    int t = bt % 77, bb = bt / 77;
    x[((size_t)(bb * 126 + 49 + t)) * 512 + d] =
        ld_f(txt, idx, fla) + ld_f(pos, (49 + t) * 512 + d, fla);
  }
}

// ---------------------------------------------------------------------------
extern "C" void kernel_launch(void* const* d_in, const int* in_sizes, int n_in,
                              void* d_out, int out_size, void* d_ws, size_t ws_size,
                              hipStream_t stream)
{
  (void)in_sizes; (void)n_in; (void)out_size;
  const void* img_hidden = d_in[0];
  const void* txt_emb    = d_in[1];
  const void* img_proj_w = d_in[2];
  const void* img_proj_b = d_in[3];
  const void* pos_embed  = d_in[4];
  const void* wq    = d_in[5];
  const void* wk    = d_in[6];
  const void* wv    = d_in[7];
  const void* w_proj = d_in[8];
  const void* b_proj = d_in[9];
  const void* ln1_g = d_in[10];
  const void* ln1_b = d_in[11];
  const void* ln2_g = d_in[12];
  const void* ln2_b = d_in[13];
  const void* fc1_w = d_in[14];
  const void* fc1_b = d_in[15];
  const void* fc2_w = d_in[16];
  const void* fc2_b = d_in[17];
  const void* lnf_g = d_in[18];
  const void* lnf_b = d_in[19];
  const void* out_w = d_in[20];
  const void* out_b = d_in[21];
  const int* amask  = (const int*)d_in[22];

  char* ws = (char*)d_ws;
  size_t off = 0;
  auto alloc = [&](size_t bytes) {
    void* p = ws + off; off += (bytes + 255) & ~(size_t)255; return p;
  };
  int* dflag = (int*)alloc(256);
  u16* imgbf = (u16*)alloc(1204224ull * 2);
  float* x   = (float*)alloc(4032ull * 512 * 4);
  u16* xl    = (u16*)alloc(2464ull * 512 * 2);
  const size_t uni0 = off;
  u16* imgwT = (u16*)alloc(512ull * 768 * 2);
  u16* qkvT  = (u16*)alloc(4ull * 1536 * 512 * 2);
  u16* wpT   = (u16*)alloc(4ull * 512 * 512 * 2);
  u16* fc1T  = (u16*)alloc(4ull * 2048 * 512 * 2);
  u16* fc2T  = (u16*)alloc(4ull * 512 * 2048 * 2);
  u16* h     = (u16*)alloc(4032ull * 512 * 2);
  u16* qkvb  = (u16*)alloc(4032ull * 1536 * 2);
  u16* ob    = (u16*)alloc(4032ull * 512 * 2);
  u16* ff    = (u16*)alloc(4032ull * 2048 * 2);
  u16* outwT = (u16*)(ws + uni0);   // 50.6 MB, aliases dead loop buffers

  if (ws_size < off) {
    sentinel_kernel<<<dim3(16), 256, 0, stream>>>((float*)d_out);
    return;
  }

  detect_kernel<<<dim3(1), 64, 0, stream>>>(img_hidden, dflag);
  convert_kernel<<<dim3(4704), 256, 0, stream>>>(img_hidden, imgbf, 1204224, dflag);

  transpose_any<<<dim3(16, 24, 1), 256, 0, stream>>>(img_proj_w, imgwT, 768, 512, dflag);
  transpose_qkv<<<dim3(2, 16, 32), 256, 0, stream>>>(wq, qkvT, 0, dflag);
  transpose_qkv<<<dim3(2, 16, 32), 256, 0, stream>>>(wk, qkvT, 512, dflag);
  transpose_qkv<<<dim3(2, 16, 32), 256, 0, stream>>>(wv, qkvT, 1024, dflag);
  transpose_any<<<dim3(16, 16, 4), 256, 0, stream>>>(w_proj, wpT, 512, 512, dflag);
  transpose_any<<<dim3(64, 16, 4), 256, 0, stream>>>(fc1_w, fc1T, 512, 2048, dflag);
  transpose_any<<<dim3(16, 64, 4), 256, 0, stream>>>(fc2_w, fc2T, 2048, 512, dflag);

  gemm_kernel<64, 128, 3><<<dim3(100), 256, 0, stream>>>(
      imgbf, imgwT, x, img_proj_b, 0, nullptr, pos_embed, 1568, 512, 768, 25, dflag);
  txt_embed_kernel<<<dim3(4928), 256, 0, stream>>>(txt_emb, pos_embed, x, dflag);

  for (int i = 0; i < 4; ++i) {
    ln_kernel<0><<<dim3(4032), 256, 0, stream>>>(x, ln1_g, ln1_b, i * 512, h, dflag);
    gemm_kernel<64, 128, 0><<<dim3(756), 256, 0, stream>>>(
        h, qkvT + i * 786432, qkvb, nullptr, 0, nullptr, nullptr, 4032, 1536, 512, 63, dflag);
    attn_kernel<<<dim3(32, 8, 2), 256, 0, stream>>>(qkvb, amask, ob);
    gemm_kernel<64, 128, 2><<<dim3(252), 256, 0, stream>>>(
        ob, wpT + i * 262144, x, b_proj, i * 512, x, nullptr, 4032, 512, 512, 63, dflag);
    ln_kernel<0><<<dim3(4032), 256, 0, stream>>>(x, ln2_g, ln2_b, i * 512, h, dflag);
    gemm_kernel<64, 128, 1><<<dim3(1008), 256, 0, stream>>>(
        h, fc1T + i * 1048576, ff, fc1_b, i * 2048, nullptr, nullptr, 4032, 2048, 512, 63, dflag);
    gemm_kernel<64, 128, 2><<<dim3(252), 256, 0, stream>>>(
        ff, fc2T + i * 1048576, x, fc2_b, i * 512, x, nullptr, 4032, 512, 2048, 63, dflag);
  }

  ln_kernel<1><<<dim3(2464), 256, 0, stream>>>(x, lnf_g, lnf_b, 0, xl, dflag);
  transpose_any<<<dim3(1544, 16, 1), 256, 0, stream>>>(out_w, outwT, 512, 49408, dflag);
  gemm_kernel<128, 128, 4><<<dim3(7720), 256, 0, stream>>>(
      xl, outwT, d_out, out_b, 0, nullptr, nullptr, 2464, 49408, 512, 20, dflag);
}

// Round 7
// 1032.459 us; speedup vs baseline: 1.5520x; 1.0291x over previous
//
#include <hip/hip_runtime.h>
#include <hip/hip_bf16.h>
#include <stdint.h>

// ---------------------------------------------------------------------------
// MMTransformer: B=32, IMG_LEN=49, TXT_LEN=77, L=126, D=512, H=8, HK=64,
// FF=2048, NB=4, IMG_DIM=768, VOCAB=49408.
// Round 6: vocab GEMM -> 256x256 tile, 8 waves (2Mx4N), BK=64, 2-phase
// dbuf pipeline (64 MFMA/wave per barrier, 2.7:1 MFMA:ds_read); layer GEMMs
// stay 64x128 (grid width). Merged qkv weight transposes into one launch.
// Retained: both-sides chunk-XOR LDS swizzle, bijective XCD swizzle,
// LDS-coalesced epilogues, runtime input-dtype detection.
// ---------------------------------------------------------------------------

using u16 = unsigned short;
typedef __attribute__((ext_vector_type(8))) __bf16 bf16x8v;
typedef __attribute__((ext_vector_type(4))) float f32x4;

__device__ __forceinline__ float bf2f(u16 u) {
  union { unsigned int i; float f; } x; x.i = ((unsigned int)u) << 16; return x.f;
}
__device__ __forceinline__ u16 f2bf(float f) {
  union { float f; unsigned int i; } u; u.f = f;
  unsigned int r = u.i + 0x7FFFu + ((u.i >> 16) & 1u);   // RNE
  return (u16)(r >> 16);
}
__device__ __forceinline__ float ld_f(const void* p, size_t i, int fl) {
  return fl ? ((const float*)p)[i] : bf2f(((const u16*)p)[i]);
}
__device__ __forceinline__ u16 ld_bf(const void* p, size_t i, int fl) {
  return fl ? f2bf(((const float*)p)[i]) : ((const u16*)p)[i];
}

// async global->LDS, 16B per lane; LDS dest = wave-uniform base + lane*16.
__device__ __forceinline__ void async_copy16(const void* g, void* l) {
  __builtin_amdgcn_global_load_lds(
      (__attribute__((address_space(1))) void*)(g),
      (__attribute__((address_space(3))) void*)(l), 16, 0, 0);
}

// dtype detector: img_hidden ~ N(0,1). bf16 buffer -> ~0 implausible u16s;
// f32 buffer -> even-index u16s are mantissa bits, ~50-60% implausible.
__global__ void detect_kernel(const void* __restrict__ img, int* __restrict__ flag) {
  const int lane = threadIdx.x;
  const u16* p = (const u16*)img;
  int bad = 0;
#pragma unroll
  for (int i = 0; i < 4; ++i) {
    float v = bf2f(p[lane * 4 + i]);
    float av = fabsf(v);
    if (!(av <= 1e4f) || (av != 0.0f && av < 1e-30f)) bad++;
  }
#pragma unroll
  for (int off = 32; off; off >>= 1) bad += __shfl_xor(bad, off, 64);
  if (lane == 0) flag[0] = (bad > 16) ? 1 : 0;
}

__global__ void sentinel_kernel(float* out) {
  out[blockIdx.x * 256 + threadIdx.x] = 123456.0f;
}

__global__ __launch_bounds__(256) void convert_kernel(
    const void* __restrict__ in, u16* __restrict__ out, int n,
    const int* __restrict__ fl) {
  const int fla = *fl;
  int i = blockIdx.x * 256 + threadIdx.x;
  if (i < n) out[i] = ld_bf(in, i, fla);
}

// ---------------------------------------------------------------------------
// 64/128-row bf16 MFMA GEMM (layer GEMMs): BN=128, BK=64, 2-phase dbuf.
// ---------------------------------------------------------------------------
template <int BM, int BN, int EPI>
__global__ __launch_bounds__(256) void gemm_kernel(
    const u16* __restrict__ A, const u16* __restrict__ Bt, void* Cout,
    const void* __restrict__ bias, long boff, const float* resid,
    const void* __restrict__ pos, int M, int N, int K, int gridM,
    const int* __restrict__ fl)
{
  static_assert(BN == 128, "");
  static_assert(BM == 64 || BM == 128, "");
  constexpr int TILE_B = (BM + BN) * 128;               // bytes per K-tile buf
  constexpr int EPI_B = BM * BN * 2;
  constexpr int SMEM_B = (2 * TILE_B > EPI_B) ? 2 * TILE_B : EPI_B;
  __shared__ __align__(16) char smem[SMEM_B];

  const int tid = threadIdx.x;
  const int lane = tid & 63, wid = tid >> 6;
  const int wm = wid >> 1, wn = wid & 1;                // 2x2 wave grid
  constexpr int FM = BM / 32, FN = 4;
  constexpr int ITA = BM / 32, ITB = BN / 32;           // gload_lds per wave

  // bijective XCD swizzle (m204), then M-fastest decomposition
  const int nwg = gridDim.x;
  const int q = nwg >> 3, r8 = nwg & 7;
  const int xcd = blockIdx.x & 7, idx = blockIdx.x >> 3;
  const int wgid = (xcd < r8 ? xcd * (q + 1) : r8 * (q + 1) + (xcd - r8) * q) + idx;
  const int tileM = (wgid % gridM) * BM, tileN = (wgid / gridM) * BN;

  f32x4 acc[FM][FN] = {};

  auto stage = [&](int buf, int kt) {
    char* base = smem + buf * TILE_B;
#pragma unroll
    for (int it = 0; it < ITA; ++it) {
      int ch = (wid * ITA + it) * 64 + lane;            // linear 16B chunk
      int row = ch >> 3, slot = ch & 7;
      int grow = tileM + row; grow = grow < M ? grow : (M - 1);
      async_copy16(A + (size_t)grow * K + kt * 64 + ((slot ^ (row & 7)) << 3),
                   base + (wid * ITA + it) * 1024);
    }
#pragma unroll
    for (int it = 0; it < ITB; ++it) {
      int ch = (wid * ITB + it) * 64 + lane;
      int row = ch >> 3, slot = ch & 7;
      async_copy16(Bt + (size_t)(tileN + row) * K + kt * 64 + ((slot ^ (row & 7)) << 3),
                   base + BM * 128 + (wid * ITB + it) * 1024);
    }
  };

  const int kSteps = K >> 6;
  stage(0, 0);
  __syncthreads();                       // drains vmcnt(0): buf0 ready
  int cur = 0;
  for (int kt = 0; kt < kSteps; ++kt) {
    if (kt + 1 < kSteps) stage(cur ^ 1, kt + 1);   // prefetch next K-tile
    const u16* lA = (const u16*)(smem + cur * TILE_B);
    const u16* lB = (const u16*)(smem + cur * TILE_B + BM * 128);
#pragma unroll
    for (int kk = 0; kk < 2; ++kk) {
      const int j = kk * 4 + (lane >> 4);             // logical k-chunk
      bf16x8v af[FM], bfr[FN];
#pragma unroll
      for (int fm = 0; fm < FM; ++fm) {
        int rr = wm * (BM / 2) + fm * 16 + (lane & 15);
        af[fm] = *(const bf16x8v*)(lA + rr * 64 + ((j ^ (rr & 7)) << 3));
      }
#pragma unroll
      for (int fn = 0; fn < FN; ++fn) {
        int rn = wn * 64 + fn * 16 + (lane & 15);
        bfr[fn] = *(const bf16x8v*)(lB + rn * 64 + ((j ^ (rn & 7)) << 3));
      }
#pragma unroll
      for (int fm = 0; fm < FM; ++fm)
#pragma unroll
        for (int fn = 0; fn < FN; ++fn)
          acc[fm][fn] = __builtin_amdgcn_mfma_f32_16x16x32_bf16(
              af[fm], bfr[fn], acc[fm][fn], 0, 0, 0);
    }
    __syncthreads();                     // readers done + next buf ready
    cur ^= 1;
  }

  const int fla = (EPI == 0) ? 0 : *fl;
  const int row0l = wm * (BM / 2);
  const int col0l = wn * 64;

  auto store_bf16 = [&](bool do_bias, bool do_gelu) {
    u16* ep = (u16*)smem;
#pragma unroll
    for (int fm = 0; fm < FM; ++fm)
#pragma unroll
      for (int fn = 0; fn < FN; ++fn)
#pragma unroll
        for (int jj = 0; jj < 4; ++jj) {
          int rl = row0l + fm * 16 + ((lane >> 4) << 2) + jj;
          int cl = col0l + fn * 16 + (lane & 15);
          float t = acc[fm][fn][jj];
          if (do_bias) t += ld_f(bias, boff + tileN + cl, fla);
          if (do_gelu) t = 0.5f * t * (1.0f + erff(t * 0.70710678118654752f));
          ep[rl * BN + cl] = f2bf(t);
        }
    __syncthreads();
    for (int rr = tid >> 4; rr < BM; rr += 16) {
      int grow = tileM + rr;
      if (grow < M)
        *(uint4*)((u16*)Cout + (size_t)grow * N + tileN + (tid & 15) * 8) =
            *(const uint4*)(ep + rr * BN + (tid & 15) * 8);
    }
  };

  auto store_f32 = [&](bool do_resid, bool do_remap_pos) {
    float* epf = (float*)smem;
#pragma unroll
    for (int p = 0; p < 2; ++p) {
      __syncthreads();
      if (wm == p) {
#pragma unroll
        for (int fm = 0; fm < FM; ++fm)
#pragma unroll
          for (int fn = 0; fn < FN; ++fn)
#pragma unroll
            for (int jj = 0; jj < 4; ++jj) {
              int rl = fm * 16 + ((lane >> 4) << 2) + jj;
              int cl = col0l + fn * 16 + (lane & 15);
              float t = acc[fm][fn][jj] + ld_f(bias, boff + tileN + cl, fla);
              if (do_remap_pos) {
                int grow_t = tileM + p * (BM / 2) + rl;
                int ll = grow_t % 49;
                t += ld_f(pos, ll * 512 + tileN + cl, fla);
              }
              epf[rl * BN + cl] = t;
            }
      }
      __syncthreads();
      for (int rr = tid >> 5; rr < BM / 2; rr += 8) {
        int grow = tileM + p * (BM / 2) + rr;
        if (grow < M) {
          f32x4 t = *(const f32x4*)(epf + rr * BN + (tid & 31) * 4);
          if (do_resid)
            t += *(const f32x4*)(resid + (size_t)grow * N + tileN + (tid & 31) * 4);
          size_t orow = grow;
          if (do_remap_pos) orow = (size_t)(grow / 49) * 126 + grow % 49;
          *(f32x4*)((float*)Cout + orow * N + tileN + (tid & 31) * 4) = t;
        }
      }
    }
  };

  if constexpr (EPI == 0) store_bf16(false, false);
  else if constexpr (EPI == 1) store_bf16(true, true);
  else if constexpr (EPI == 2) store_f32(true, false);
  else if constexpr (EPI == 3) store_f32(false, true);
  else { if (fla) store_f32(false, false); else store_bf16(true, false); }
}

// ---------------------------------------------------------------------------
// 256x256 vocab GEMM: 512 threads = 8 waves (2M x 4N), BK=64, 2-phase dbuf.
// Per wave: 128x64 output, FM=8, FN=4, 64 MFMA per K-step per barrier-pair.
// LDS 128 KiB (2 x 64 KiB K-tile buffers); epilogue reuses smem.
// Epilogue: acc + bias -> d_out (f32 or bf16 per flag), coalesced.
// ---------------------------------------------------------------------------
__global__ __launch_bounds__(512) void gemm256_kernel(
    const u16* __restrict__ A, const u16* __restrict__ Bt, void* Cout,
    const void* __restrict__ bias, int M, int N, int K, int gridM,
    const int* __restrict__ fl)
{
  constexpr int BM = 256, BN = 256;
  constexpr int TILE_B = (BM + BN) * 128;               // 64 KiB per buffer
  __shared__ __align__(16) char smem[2 * TILE_B];       // 128 KiB

  const int tid = threadIdx.x;
  const int lane = tid & 63, wid = tid >> 6;
  const int wm = wid >> 2, wn = wid & 3;                // 2M x 4N wave grid

  const int nwg = gridDim.x;
  const int q = nwg >> 3, r8 = nwg & 7;
  const int xcd = blockIdx.x & 7, idx = blockIdx.x >> 3;
  const int wgid = (xcd < r8 ? xcd * (q + 1) : r8 * (q + 1) + (xcd - r8) * q) + idx;
  const int tileM = (wgid % gridM) * BM, tileN = (wgid / gridM) * BN;

  f32x4 acc[8][4] = {};

  auto stage = [&](int buf, int kt) {
    char* base = smem + buf * TILE_B;
#pragma unroll
    for (int it = 0; it < 4; ++it) {                    // A: 256 rows
      int ch = (wid * 4 + it) * 64 + lane;              // 0..2047
      int row = ch >> 3, slot = ch & 7;
      int grow = tileM + row; grow = grow < M ? grow : (M - 1);
      async_copy16(A + (size_t)grow * K + kt * 64 + ((slot ^ (row & 7)) << 3),
                   base + (wid * 4 + it) * 1024);
    }
#pragma unroll
    for (int it = 0; it < 4; ++it) {                    // B: 256 rows
      int ch = (wid * 4 + it) * 64 + lane;
      int row = ch >> 3, slot = ch & 7;
      async_copy16(Bt + (size_t)(tileN + row) * K + kt * 64 + ((slot ^ (row & 7)) << 3),
                   base + BM * 128 + (wid * 4 + it) * 1024);
    }
  };

  const int kSteps = K >> 6;
  stage(0, 0);
  __syncthreads();
  int cur = 0;
  for (int kt = 0; kt < kSteps; ++kt) {
    if (kt + 1 < kSteps) stage(cur ^ 1, kt + 1);
    const u16* lA = (const u16*)(smem + cur * TILE_B);
    const u16* lB = (const u16*)(smem + cur * TILE_B + BM * 128);
#pragma unroll
    for (int kk = 0; kk < 2; ++kk) {
      const int j = kk * 4 + (lane >> 4);
      bf16x8v af[8], bfr[4];
#pragma unroll
      for (int fm = 0; fm < 8; ++fm) {
        int rr = wm * 128 + fm * 16 + (lane & 15);
        af[fm] = *(const bf16x8v*)(lA + rr * 64 + ((j ^ (rr & 7)) << 3));
      }
#pragma unroll
      for (int fn = 0; fn < 4; ++fn) {
        int rn = wn * 64 + fn * 16 + (lane & 15);
        bfr[fn] = *(const bf16x8v*)(lB + rn * 64 + ((j ^ (rn & 7)) << 3));
      }
#pragma unroll
      for (int fm = 0; fm < 8; ++fm)
#pragma unroll
        for (int fn = 0; fn < 4; ++fn)
          acc[fm][fn] = __builtin_amdgcn_mfma_f32_16x16x32_bf16(
              af[fm], bfr[fn], acc[fm][fn], 0, 0, 0);
    }
    __syncthreads();
    cur ^= 1;
  }

  const int fla = *fl;
  if (fla) {
    // f32 out: 4 quarter passes (64 rows x 256 cols f32 = 64 KiB in LDS).
    float* epf = (float*)smem;
#pragma unroll
    for (int p = 0; p < 4; ++p) {
      __syncthreads();
      if (wm == (p >> 1)) {
#pragma unroll
        for (int fq = 0; fq < 4; ++fq) {
          int fm = (p & 1) * 4 + fq;
#pragma unroll
          for (int fn = 0; fn < 4; ++fn)
#pragma unroll
            for (int jj = 0; jj < 4; ++jj) {
              int rl = fq * 16 + ((lane >> 4) << 2) + jj;      // 0..63
              int cl = wn * 64 + fn * 16 + (lane & 15);
              epf[rl * 256 + cl] = acc[fm][fn][jj] + ld_f(bias, tileN + cl, 1);
            }
        }
      }
      __syncthreads();
      for (int rr = tid >> 6; rr < 64; rr += 8) {
        int grow = tileM + p * 64 + rr;
        if (grow < M)
          *(f32x4*)((float*)Cout + (size_t)grow * N + tileN + lane * 4) =
              *(const f32x4*)(epf + rr * 256 + lane * 4);
      }
    }
  } else {
    // bf16 out: full 256x256 u16 stage (128 KiB).
    u16* ep = (u16*)smem;
    __syncthreads();
#pragma unroll
    for (int fm = 0; fm < 8; ++fm)
#pragma unroll
      for (int fn = 0; fn < 4; ++fn)
#pragma unroll
        for (int jj = 0; jj < 4; ++jj) {
          int rl = wm * 128 + fm * 16 + ((lane >> 4) << 2) + jj;
          int cl = wn * 64 + fn * 16 + (lane & 15);
          ep[rl * 256 + cl] = f2bf(acc[fm][fn][jj] + ld_f(bias, tileN + cl, 0));
        }
    __syncthreads();
    for (int rr = tid >> 5; rr < 256; rr += 16) {
      int grow = tileM + rr;
      if (grow < M)
        *(uint4*)((u16*)Cout + (size_t)grow * N + tileN + (tid & 31) * 8) =
            *(const uint4*)(ep + rr * 256 + (tid & 31) * 8);
    }
  }
}

// 32x32 tiled transpose: in [R][C] (flag dtype, z-batched) -> out [C][R] bf16.
__global__ __launch_bounds__(256) void transpose_any(
    const void* __restrict__ in, u16* __restrict__ out, int R, int C,
    const int* __restrict__ fl)
{
  const int fla = *fl;
  __shared__ u16 t[32][33];
  const size_t zo = (size_t)blockIdx.z * R * C;
  const int c0 = blockIdx.x * 32, r0 = blockIdx.y * 32;
  const int tx = threadIdx.x & 31, ty = threadIdx.x >> 5;
#pragma unroll
  for (int i = 0; i < 4; ++i)
    t[ty + 8 * i][tx] = ld_bf(in, zo + (size_t)(r0 + ty + 8 * i) * C + (c0 + tx), fla);
  __syncthreads();
#pragma unroll
  for (int i = 0; i < 4; ++i)
    out[zo + (size_t)(c0 + ty + 8 * i) * R + (r0 + tx)] = t[tx][ty + 8 * i];
}

// All three qkv weight tensors in one launch. z in [0,96): src=z>>5,
// rem=z&31, layer=rem>>3, head=rem&7. in [4][8][512][64] -> qkvT rows.
__global__ __launch_bounds__(256) void transpose_qkv3(
    const void* __restrict__ wq, const void* __restrict__ wk,
    const void* __restrict__ wv, u16* __restrict__ out,
    const int* __restrict__ fl)
{
  const int fla = *fl;
  __shared__ u16 t[32][33];
  const int z = blockIdx.z, src = z >> 5, rem = z & 31, li = rem >> 3, hh = rem & 7;
  const void* in = (src == 0) ? wq : (src == 1) ? wk : wv;
  const size_t zi = (size_t)rem * 512 * 64;
  const size_t zo = (size_t)li * (1536 * 512) + (size_t)(src * 512 + hh * 64) * 512;
  const int c0 = blockIdx.x * 32, r0 = blockIdx.y * 32;
  const int tx = threadIdx.x & 31, ty = threadIdx.x >> 5;
#pragma unroll
  for (int i = 0; i < 4; ++i)
    t[ty + 8 * i][tx] = ld_bf(in, zi + (size_t)(r0 + ty + 8 * i) * 64 + (c0 + tx), fla);
  __syncthreads();
#pragma unroll
  for (int i = 0; i < 4; ++i)
    out[zo + (size_t)(c0 + ty + 8 * i) * 512 + (r0 + tx)] = t[tx][ty + 8 * i];
}

// Attention: one block per (b, h, row-half). qkv packed [B*L][1536].
__global__ __launch_bounds__(256) void attn_kernel(
    const u16* __restrict__ qkv, const int* __restrict__ amask,
    u16* __restrict__ o)
{
  const int b = blockIdx.x, hh = blockIdx.y, half = blockIdx.z;
  __shared__ float Kf[126 * 65];
  __shared__ u16 Vh[126 * 65];
  __shared__ float P[4][128];
  __shared__ float padK[128];
  const int tid = threadIdx.x, lane = tid & 63, wid = tid >> 6;

  for (int idx = tid; idx < 126 * 64; idx += 256) {
    int m = idx >> 6, kk = idx & 63;
    size_t base = ((size_t)(b * 126 + m)) * 1536 + hh * 64 + kk;
    Kf[m * 65 + kk] = bf2f(qkv[base + 512]);
    Vh[m * 65 + kk] = qkv[base + 1024];
  }
  for (int j = tid; j < 128; j += 256) {
    float kv = 0.0f;
    if (j < 49) kv = 1.0f;
    else if (j < 126) kv = (amask[b * 77 + (j - 49)] != 0) ? 1.0f : 0.0f;
    padK[j] = kv;
  }
  __syncthreads();

  const float scale = 0.04419417382415922f;  // 512^-0.5 (full-D, faithful)
  const int lbase = half * 63;
  for (int l = lbase + wid; l < lbase + 63; l += 4) {
    float qv = bf2f(qkv[((size_t)(b * 126 + l)) * 1536 + hh * 64 + lane]);
    const int m0 = lane;
    const int m1v = lane + 64;
    const int m1 = m1v < 126 ? m1v : 125;
    const float* K0 = Kf + m0 * 65;
    const float* K1 = Kf + m1 * 65;
    float s0 = 0.f, s1 = 0.f;
#pragma unroll 8
    for (int kk = 0; kk < 64; ++kk) {
      float qs = __shfl(qv, kk, 64);
      s0 += qs * K0[kk];
      s1 += qs * K1[kk];
    }
    s0 *= scale; s1 *= scale;
    bool kp0 = (padK[m0] != 0.f) && (m0 < 49 || l < 49 || m0 <= l);
    bool kp1 = (padK[m1v] != 0.f) && (l < 49 || m1v <= l);
    float e0 = kp0 ? s0 : -1e30f;
    float e1 = kp1 ? s1 : -1e30f;
    float mx = fmaxf(e0, e1);
#pragma unroll
    for (int off = 32; off; off >>= 1) mx = fmaxf(mx, __shfl_xor(mx, off, 64));
    float p0 = kp0 ? __expf(s0 - mx) : 0.f;
    float p1 = kp1 ? __expf(s1 - mx) : 0.f;
    float sm = p0 + p1;
#pragma unroll
    for (int off = 32; off; off >>= 1) sm += __shfl_xor(sm, off, 64);
    float inv = 1.0f / sm;
    P[wid][lane] = p0 * inv;
    P[wid][lane + 64] = p1 * inv;
    float accv = 0.f;
#pragma unroll 6
    for (int m = 0; m < 126; ++m) accv += P[wid][m] * bf2f(Vh[m * 65 + lane]);
    o[((size_t)(b * 126 + l)) * 512 + hh * 64 + lane] = f2bf(accv);
  }
}

// LayerNorm over D=512 (x f32 -> bf16). goff = element offset into gam/bet.
template <int REMAP>
__global__ __launch_bounds__(256) void ln_kernel(
    const float* __restrict__ x, const void* __restrict__ gam,
    const void* __restrict__ bet, long goff, u16* __restrict__ out,
    const int* __restrict__ fl)
{
  const int fla = *fl;
  const int r = blockIdx.x;
  int srow, drow;
  if constexpr (REMAP) { int bb = r / 77, t = r % 77; srow = bb * 126 + 49 + t; drow = r; }
  else { srow = r; drow = r; }
  const float* xr = x + (size_t)srow * 512;
  const int tid = threadIdx.x, lane = tid & 63, wid = tid >> 6;
  float a = xr[tid], c = xr[tid + 256];
  float s = a + c;
#pragma unroll
  for (int off = 32; off; off >>= 1) s += __shfl_xor(s, off, 64);
  __shared__ float red0[4], red1[4];
  if (lane == 0) red0[wid] = s;
  __syncthreads();
  float mu = (red0[0] + red0[1] + red0[2] + red0[3]) * (1.0f / 512.0f);
  float da = a - mu, dc = c - mu;
  float q2 = da * da + dc * dc;
#pragma unroll
  for (int off = 32; off; off >>= 1) q2 += __shfl_xor(q2, off, 64);
  if (lane == 0) red1[wid] = q2;
  __syncthreads();
  float var = (red1[0] + red1[1] + red1[2] + red1[3]) * (1.0f / 512.0f);
  float inv = rsqrtf(var + 1e-5f);
  u16* orow = out + (size_t)drow * 512;
  orow[tid] = f2bf(da * inv * ld_f(gam, goff + tid, fla) + ld_f(bet, goff + tid, fla));
  orow[tid + 256] =
      f2bf(dc * inv * ld_f(gam, goff + tid + 256, fla) + ld_f(bet, goff + tid + 256, fla));
}

__global__ __launch_bounds__(256) void txt_embed_kernel(
    const void* __restrict__ txt, const void* __restrict__ pos,
    float* __restrict__ x, const int* __restrict__ fl)
{
  const int fla = *fl;
  int idx = blockIdx.x * 256 + threadIdx.x;
  if (idx < 32 * 77 * 512) {
    int d = idx & 511;
    int bt = idx >> 9;
    int t = bt % 77, bb = bt / 77;
    x[((size_t)(bb * 126 + 49 + t)) * 512 + d] =
        ld_f(txt, idx, fla) + ld_f(pos, (49 + t) * 512 + d, fla);
  }
}

// ---------------------------------------------------------------------------
extern "C" void kernel_launch(void* const* d_in, const int* in_sizes, int n_in,
                              void* d_out, int out_size, void* d_ws, size_t ws_size,
                              hipStream_t stream)
{
  (void)in_sizes; (void)n_in; (void)out_size;
  const void* img_hidden = d_in[0];
  const void* txt_emb    = d_in[1];
  const void* img_proj_w = d_in[2];
  const void* img_proj_b = d_in[3];
  const void* pos_embed  = d_in[4];
  const void* wq    = d_in[5];
  const void* wk    = d_in[6];
  const void* wv    = d_in[7];
  const void* w_proj = d_in[8];
  const void* b_proj = d_in[9];
  const void* ln1_g = d_in[10];
  const void* ln1_b = d_in[11];
  const void* ln2_g = d_in[12];
  const void* ln2_b = d_in[13];
  const void* fc1_w = d_in[14];
  const void* fc1_b = d_in[15];
  const void* fc2_w = d_in[16];
  const void* fc2_b = d_in[17];
  const void* lnf_g = d_in[18];
  const void* lnf_b = d_in[19];
  const void* out_w = d_in[20];
  const void* out_b = d_in[21];
  const int* amask  = (const int*)d_in[22];

  char* ws = (char*)d_ws;
  size_t off = 0;
  auto alloc = [&](size_t bytes) {
    void* p = ws + off; off += (bytes + 255) & ~(size_t)255; return p;
  };
  int* dflag = (int*)alloc(256);
  u16* imgbf = (u16*)alloc(1204224ull * 2);
  float* x   = (float*)alloc(4032ull * 512 * 4);
  u16* xl    = (u16*)alloc(2464ull * 512 * 2);
  const size_t uni0 = off;
  u16* imgwT = (u16*)alloc(512ull * 768 * 2);
  u16* qkvT  = (u16*)alloc(4ull * 1536 * 512 * 2);
  u16* wpT   = (u16*)alloc(4ull * 512 * 512 * 2);
  u16* fc1T  = (u16*)alloc(4ull * 2048 * 512 * 2);
  u16* fc2T  = (u16*)alloc(4ull * 512 * 2048 * 2);
  u16* h     = (u16*)alloc(4032ull * 512 * 2);
  u16* qkvb  = (u16*)alloc(4032ull * 1536 * 2);
  u16* ob    = (u16*)alloc(4032ull * 512 * 2);
  u16* ff    = (u16*)alloc(4032ull * 2048 * 2);
  u16* outwT = (u16*)(ws + uni0);   // 50.6 MB, aliases dead loop buffers

  if (ws_size < off) {
    sentinel_kernel<<<dim3(16), 256, 0, stream>>>((float*)d_out);
    return;
  }

  detect_kernel<<<dim3(1), 64, 0, stream>>>(img_hidden, dflag);
  convert_kernel<<<dim3(4704), 256, 0, stream>>>(img_hidden, imgbf, 1204224, dflag);

  transpose_any<<<dim3(16, 24, 1), 256, 0, stream>>>(img_proj_w, imgwT, 768, 512, dflag);
  transpose_qkv3<<<dim3(2, 16, 96), 256, 0, stream>>>(wq, wk, wv, qkvT, dflag);
  transpose_any<<<dim3(16, 16, 4), 256, 0, stream>>>(w_proj, wpT, 512, 512, dflag);
  transpose_any<<<dim3(64, 16, 4), 256, 0, stream>>>(fc1_w, fc1T, 512, 2048, dflag);
  transpose_any<<<dim3(16, 64, 4), 256, 0, stream>>>(fc2_w, fc2T, 2048, 512, dflag);

  gemm_kernel<64, 128, 3><<<dim3(100), 256, 0, stream>>>(
      imgbf, imgwT, x, img_proj_b, 0, nullptr, pos_embed, 1568, 512, 768, 25, dflag);
  txt_embed_kernel<<<dim3(4928), 256, 0, stream>>>(txt_emb, pos_embed, x, dflag);

  for (int i = 0; i < 4; ++i) {
    ln_kernel<0><<<dim3(4032), 256, 0, stream>>>(x, ln1_g, ln1_b, i * 512, h, dflag);
    gemm_kernel<64, 128, 0><<<dim3(756), 256, 0, stream>>>(
        h, qkvT + i * 786432, qkvb, nullptr, 0, nullptr, nullptr, 4032, 1536, 512, 63, dflag);
    attn_kernel<<<dim3(32, 8, 2), 256, 0, stream>>>(qkvb, amask, ob);
    gemm_kernel<64, 128, 2><<<dim3(252), 256, 0, stream>>>(
        ob, wpT + i * 262144, x, b_proj, i * 512, x, nullptr, 4032, 512, 512, 63, dflag);
    ln_kernel<0><<<dim3(4032), 256, 0, stream>>>(x, ln2_g, ln2_b, i * 512, h, dflag);
    gemm_kernel<64, 128, 1><<<dim3(1008), 256, 0, stream>>>(
        h, fc1T + i * 1048576, ff, fc1_b, i * 2048, nullptr, nullptr, 4032, 2048, 512, 63, dflag);
    gemm_kernel<64, 128, 2><<<dim3(252), 256, 0, stream>>>(
        ff, fc2T + i * 1048576, x, fc2_b, i * 512, x, nullptr, 4032, 512, 2048, 63, dflag);
  }

  ln_kernel<1><<<dim3(2464), 256, 0, stream>>>(x, lnf_g, lnf_b, 0, xl, dflag);
  transpose_any<<<dim3(1544, 16, 1), 256, 0, stream>>>(out_w, outwT, 512, 49408, dflag);
  gemm256_kernel<<<dim3(1930), 512, 0, stream>>>(
      xl, outwT, d_out, out_b, 2464, 49408, 512, 10, dflag);
}